// Round 15
// baseline (199.676 us; speedup 1.0000x reference)
//
#include <hip/hip_runtime.h>

using u16   = unsigned short;
using f32x4 = __attribute__((ext_vector_type(4))) float;
using s16x8 = __attribute__((ext_vector_type(8))) short;
using u32x2 = __attribute__((ext_vector_type(2))) unsigned int;
using u32x4 = __attribute__((ext_vector_type(4))) unsigned int;

#define LOG2E 1.44269504088896f

static __device__ __forceinline__ u16 f2bf(float f) {
  union { float f; unsigned u; } a; a.f = f;
  unsigned r = a.u + 0x7fffu + ((a.u >> 16) & 1u);
  return (u16)(r >> 16);
}
// pack two f32 -> u32 of 2 bf16 (lo = first arg), RNE
static __device__ __forceinline__ unsigned cvtpk(float lo, float hi) {
  unsigned r;
  asm("v_cvt_pk_bf16_f32 %0, %1, %2" : "=v"(r) : "v"(lo), "v"(hi));
  return r;
}

// global(16B per lane, per-lane src addr) -> LDS (wave-uniform base + lane*16)
static __device__ __forceinline__ void gload16(const void* g, void* l) {
  __builtin_amdgcn_global_load_lds(
      (__attribute__((address_space(1))) unsigned int*)g,
      (__attribute__((address_space(3))) unsigned int*)l, 16, 0, 0);
}

// bijective XCD swizzle for nb % 8 == 0
static __device__ __forceinline__ int xcd_swz(int b, int nb) {
  return (b & 7) * (nb >> 3) + (b >> 3);
}

// ---------------- merged prep: weight casts + 2x LayerNorm ----------------
__global__ __launch_bounds__(256) void prep_k(
    const float* __restrict__ Wq, const float* __restrict__ Wkv,
    const float* __restrict__ Wo, const float* __restrict__ W1,
    const float* __restrict__ W2,
    u16* __restrict__ wq_b, u16* __restrict__ wkv_b, u16* __restrict__ wo_b,
    u16* __restrict__ w1_b, u16* __restrict__ w2_b,
    const float* __restrict__ xq, const float* __restrict__ xk,
    const float* __restrict__ gq, const float* __restrict__ bq,
    const float* __restrict__ gk, const float* __restrict__ bk,
    u16* __restrict__ oq, u16* __restrict__ ok)
{
  const int blk = blockIdx.x, t = threadIdx.x;
  if (blk < 12288) {
    const int i = blk * 256 + t;   // float4-chunk id
    const float* src; u16* dst; int off; float sc = 1.0f;
    if      (i <  262144) { src = Wq;  dst = wq_b;  off = i; sc = 0.125f * LOG2E; }
    else if (i <  786432) { src = Wkv; dst = wkv_b; off = i -  262144; }
    else if (i < 1048576) { src = Wo;  dst = wo_b;  off = i -  786432; }
    else if (i < 2097152) { src = W1;  dst = w1_b;  off = i - 1048576; }
    else                  { src = W2;  dst = w2_b;  off = i - 2097152; }
    const float4 v = ((const float4*)src)[off];
    ushort4 o;
    o.x = f2bf(v.x * sc); o.y = f2bf(v.y * sc); o.z = f2bf(v.z * sc); o.w = f2bf(v.w * sc);
    ((ushort4*)dst)[off] = o;
    return;
  }
  int row = blk - 12288;
  const float* x; const float* gam; const float* bet; u16* out;
  if (row < 4096) { x = xq; gam = gq; bet = bq; out = oq; }
  else { row -= 4096; x = xk; gam = gk; bet = bk; out = ok; }
  const float4 v = ((const float4*)(x + (size_t)row * 1024))[t];
  float s  = v.x + v.y + v.z + v.w;
  float ss = v.x*v.x + v.y*v.y + v.z*v.z + v.w*v.w;
  #pragma unroll
  for (int m = 1; m < 64; m <<= 1) { s += __shfl_xor(s, m); ss += __shfl_xor(ss, m); }
  __shared__ float red[8];
  const int w = t >> 6;
  if ((t & 63) == 0) { red[w] = s; red[4 + w] = ss; }
  __syncthreads();
  s  = red[0] + red[1] + red[2] + red[3];
  ss = red[4] + red[5] + red[6] + red[7];
  const float mu   = s * (1.0f / 1024.0f);
  const float rstd = rsqrtf(ss * (1.0f / 1024.0f) - mu * mu + 1e-5f);
  const float4 gv = ((const float4*)gam)[t];
  const float4 bv = ((const float4*)bet)[t];
  ushort4 o;
  o.x = f2bf((v.x - mu) * rstd * gv.x + bv.x);
  o.y = f2bf((v.y - mu) * rstd * gv.y + bv.y);
  o.z = f2bf((v.z - mu) * rstd * gv.z + bv.z);
  o.w = f2bf((v.w - mu) * rstd * gv.w + bv.w);
  ((ushort4*)(out + (size_t)row * 1024))[t] = o;
}

// ======== GEMM 128x64, 2-buf 48KB LDS (for K=1024 GEMMs: 3 blocks/CU) ========
template<int BIAS, int RES, int SILU, int OF32, int OBF>
static __device__ __forceinline__ void gemm_body64_2buf(
    const u16* __restrict__ A, const u16* __restrict__ B,
    u16* __restrict__ Cb, float* __restrict__ Cf,
    const float* __restrict__ bias, const float* __restrict__ resid,
    int N, int K, int bid, u16* smem)
{
  const int tid = threadIdx.x;
  const int w = tid >> 6, l = tid & 63;
  const int g = l >> 4, q = l & 15;
  const int ntn = N >> 6;
  const int bm = bid / ntn, bn = bid - bm * ntn;
  const int wr = w >> 1, wc = w & 1;
  const int sw = (q & 7) << 4;
  f32x4 acc[2][2] = {};

  const size_t abase = (size_t)(bm * 128) * K;
  const size_t bbase = (size_t)(bn * 64) * K;

  auto stage = [&](int buf, int k0) {
    u16* as = smem + buf * 8192;
    u16* bs = smem + 16384 + buf * 4096;
    #pragma unroll
    for (int r = 0; r < 2; ++r) {
      const int c = (r << 9) + tid;            // A chunk 0..1023 (16B each)
      const int row = c >> 3;
      const int sp = (c & 7) ^ (row & 7);      // inverse-swizzled source part
      gload16(A + abase + (size_t)row * K + k0 + sp * 8,
              as + (size_t)((r << 9) + (w << 6)) * 8);
    }
    const int row = tid >> 3;                  // B chunk 0..511
    const int sp = (tid & 7) ^ (row & 7);
    gload16(B + bbase + (size_t)row * K + k0 + sp * 8,
            bs + (size_t)(w << 6) * 8);
  };

  const int NT = K >> 6;
  stage(0, 0);
  asm volatile("s_waitcnt vmcnt(0)" ::: "memory");
  __syncthreads();
  int cur = 0;
  for (int t = 0; t < NT; ++t) {
    if (t + 1 < NT) stage(cur ^ 1, (t + 1) << 6);
    const char* as = (const char*)(smem + cur * 8192);
    const char* bs = (const char*)(smem + 16384 + cur * 4096);
    #pragma unroll
    for (int ks = 0; ks < 2; ++ks) {
      s16x8 af[2], bfr[2];
      #pragma unroll
      for (int m = 0; m < 2; ++m)
        af[m] = *(const s16x8*)(as + (size_t)(wr * 32 + m * 16 + q) * 128 +
                                ((ks * 64 + g * 16) ^ sw));
      #pragma unroll
      for (int n = 0; n < 2; ++n)
        bfr[n] = *(const s16x8*)(bs + (size_t)(wc * 32 + n * 16 + q) * 128 +
                                 ((ks * 64 + g * 16) ^ sw));
      #pragma unroll
      for (int m = 0; m < 2; ++m)
        #pragma unroll
        for (int n = 0; n < 2; ++n)
          acc[m][n] = __builtin_amdgcn_mfma_f32_16x16x32_bf16(af[m], bfr[n], acc[m][n], 0, 0, 0);
    }
    asm volatile("s_waitcnt vmcnt(0)" ::: "memory");
    __syncthreads();
    cur ^= 1;
  }

  #pragma unroll
  for (int m = 0; m < 2; ++m) {
    const int row0 = bm * 128 + wr * 32 + m * 16 + g * 4;
    #pragma unroll
    for (int n = 0; n < 2; ++n) {
      const int col = bn * 64 + wc * 32 + n * 16 + q;
      float bv = 0.0f;
      if (BIAS) bv = bias[col];
      #pragma unroll
      for (int r = 0; r < 4; ++r) {
        const size_t idx = (size_t)(row0 + r) * N + col;
        float v = acc[m][n][r] + bv;
        if (RES)  v += resid[idx];
        if (SILU) v = v / (1.0f + __expf(-v));
        if (OF32) Cf[idx] = v;
        if (OBF)  Cb[idx] = f2bf(v);
      }
    }
  }
}

template<int BIAS, int RES, int SILU, int OF32, int OBF>
__global__ __launch_bounds__(512, 4) void gemm_k2(
    const u16* __restrict__ A, const u16* __restrict__ B,
    u16* __restrict__ Cb, float* __restrict__ Cf,
    const float* __restrict__ bias, const float* __restrict__ resid,
    int N, int K)
{
  __shared__ u16 smem[24576];
  const int bid = xcd_swz(blockIdx.x, gridDim.x);
  gemm_body64_2buf<BIAS, RES, SILU, OF32, OBF>(A, B, Cb, Cf, bias, resid, N, K, bid, smem);
}

// q-proj (512 tiles) and kv-proj (1024 tiles) merged; 3 blocks/CU co-resident
__global__ __launch_bounds__(512, 4) void gemm_qkv_k(
    const u16* __restrict__ lnq, const u16* __restrict__ wq, u16* __restrict__ qp,
    const u16* __restrict__ lnk, const u16* __restrict__ wkv, u16* __restrict__ kvp)
{
  __shared__ u16 smem[24576];
  const int sbid = xcd_swz(blockIdx.x, 1536);
  if (sbid < 512)
    gemm_body64_2buf<0,0,0,0,1>(lnq, wq, qp, nullptr, nullptr, nullptr, 1024, 1024,
                                sbid, smem);
  else
    gemm_body64_2buf<0,0,0,0,1>(lnk, wkv, kvp, nullptr, nullptr, nullptr, 2048, 1024,
                                sbid - 512, smem);
}

// ======== GEMM 128x64, 3-slot rotating LDS, counted vmcnt (for w2, K=4096) ========
template<int BIAS, int RES, int SILU, int OF32, int OBF>
__global__ __launch_bounds__(512, 4) void gemm_k3(
    const u16* __restrict__ A, const u16* __restrict__ B,
    u16* __restrict__ Cb, float* __restrict__ Cf,
    const float* __restrict__ bias, const float* __restrict__ resid,
    int N, int K)
{
  __shared__ u16 smem[36864];
  const int bid = xcd_swz(blockIdx.x, gridDim.x);
  const int tid = threadIdx.x;
  const int w = tid >> 6, l = tid & 63;
  const int g = l >> 4, q = l & 15;
  const int ntn = N >> 6;
  const int bm = bid / ntn, bn = bid - bm * ntn;
  const int wr = w >> 1, wc = w & 1;
  const int sw = (q & 7) << 4;
  f32x4 acc[2][2] = {};

  const size_t abase = (size_t)(bm * 128) * K;
  const size_t bbase = (size_t)(bn * 64) * K;

  auto stage = [&](int buf, int k0) {
    u16* as = smem + buf * 8192;
    u16* bs = smem + 24576 + buf * 4096;
    #pragma unroll
    for (int r = 0; r < 2; ++r) {
      const int c = (r << 9) + tid;            // A chunk 0..1023 (16B each)
      const int row = c >> 3;
      const int sp = (c & 7) ^ (row & 7);      // inverse-swizzled source part
      gload16(A + abase + (size_t)row * K + k0 + sp * 8,
              as + (size_t)((r << 9) + (w << 6)) * 8);
    }
    const int row = tid >> 3;                  // B chunk 0..511
    const int sp = (tid & 7) ^ (row & 7);
    gload16(B + bbase + (size_t)row * K + k0 + sp * 8,
            bs + (size_t)(w << 6) * 8);
  };

  const int NT = K >> 6;
  stage(0, 0);
  stage(1, 64);
  int cur = 0;
  for (int t = 0; t < NT; ++t) {
    if (t + 1 < NT) asm volatile("s_waitcnt vmcnt(3)" ::: "memory");
    else            asm volatile("s_waitcnt vmcnt(0)" ::: "memory");
    __builtin_amdgcn_s_barrier();
    asm volatile("" ::: "memory");
    if (t + 2 < NT) stage((cur == 0) ? 2 : cur - 1, (t + 2) << 6);

    const char* as = (const char*)(smem + cur * 8192);
    const char* bs = (const char*)(smem + 24576 + cur * 4096);
    #pragma unroll
    for (int ks = 0; ks < 2; ++ks) {
      s16x8 af[2], bfr[2];
      #pragma unroll
      for (int m = 0; m < 2; ++m)
        af[m] = *(const s16x8*)(as + (size_t)(wr * 32 + m * 16 + q) * 128 +
                                ((ks * 64 + g * 16) ^ sw));
      #pragma unroll
      for (int n = 0; n < 2; ++n)
        bfr[n] = *(const s16x8*)(bs + (size_t)(wc * 32 + n * 16 + q) * 128 +
                                 ((ks * 64 + g * 16) ^ sw));
      __builtin_amdgcn_s_setprio(1);
      #pragma unroll
      for (int m = 0; m < 2; ++m)
        #pragma unroll
        for (int n = 0; n < 2; ++n)
          acc[m][n] = __builtin_amdgcn_mfma_f32_16x16x32_bf16(af[m], bfr[n], acc[m][n], 0, 0, 0);
      __builtin_amdgcn_s_setprio(0);
    }
    cur = (cur == 2) ? 0 : cur + 1;
  }

  #pragma unroll
  for (int m = 0; m < 2; ++m) {
    const int row0 = bm * 128 + wr * 32 + m * 16 + g * 4;
    #pragma unroll
    for (int n = 0; n < 2; ++n) {
      const int col = bn * 64 + wc * 32 + n * 16 + q;
      float bv = 0.0f;
      if (BIAS) bv = bias[col];
      #pragma unroll
      for (int r = 0; r < 4; ++r) {
        const size_t idx = (size_t)(row0 + r) * N + col;
        float v = acc[m][n][r] + bv;
        if (RES)  v += resid[idx];
        if (SILU) v = v / (1.0f + __expf(-v));
        if (OF32) Cf[idx] = v;
        if (OBF)  Cb[idx] = f2bf(v);
      }
    }
  }
}

// ---------------- GEMM 256x256, BK=64, phase schedule (w1) ----------------
template<int BIAS, int RES, int SILU, int OF32, int OBF>
__global__ __launch_bounds__(512, 2) void gemm256_k(
    const u16* __restrict__ A, const u16* __restrict__ B,
    u16* __restrict__ Cb, float* __restrict__ Cf,
    const float* __restrict__ bias, const float* __restrict__ resid,
    int N, int K)
{
  __shared__ u16 smem[65536];          // 128 KB
  char* smem_c = (char*)smem;
  const int tid = threadIdx.x;
  const int w = tid >> 6, l = tid & 63;
  const int g = l >> 4, q = l & 15;
  const int wm = w >> 2, wn = w & 3;
  const int ntn = N >> 8;
  const int bid = xcd_swz(blockIdx.x, gridDim.x);
  const int bm = bid / ntn, bn = bid - bm * ntn;

  const size_t abase = (size_t)(bm * 256) * K;
  const size_t bbase = (size_t)(bn * 256) * K;

  f32x4 acc[8][4] = {};

  // part: 0=Ak0 1=Bk0 2=Ak1 3=Bk1 ; 2 loads/thread
  auto stage2 = [&](int buf, int kt, int part) {
    const int isB = part & 1, khalf = part >> 1;
    #pragma unroll
    for (int sub = 0; sub < 2; ++sub) {
      const int row  = sub * 128 + (tid >> 2);
      const int slot = (tid & 3) ^ ((row >> 1) & 3);
      const u16* src = (isB ? B + bbase : A + abase)
                     + (size_t)row * K + kt * 64 + khalf * 32 + slot * 8;
      char* dst = smem_c + buf * 65536 + isB * 32768 + khalf * 16384
                + sub * 8192 + w * 1024;   // wave-uniform; HW adds lane*16
      gload16(src, dst);
    }
  };

  const int NT = K >> 6;
  stage2(0, 0, 0); stage2(0, 0, 1); stage2(0, 0, 2); stage2(0, 0, 3);
  int cur = 0;
  const int so = (g ^ ((q >> 1) & 3)) * 16;
  for (int t = 0; t < NT; ++t) {
    const bool pre = (t + 1 < NT);
    const char* base = smem_c + cur * 65536;
    #pragma unroll
    for (int ks = 0; ks < 2; ++ks) {
      if (ks == 0 || pre) asm volatile("s_waitcnt vmcnt(4)" ::: "memory");
      else                asm volatile("s_waitcnt vmcnt(0)" ::: "memory");
      asm volatile("" ::: "memory");
      __builtin_amdgcn_s_barrier();
      asm volatile("" ::: "memory");
      const char* Ab = base + ks * 16384;
      const char* Bb = base + 32768 + ks * 16384;
      s16x8 af[8], bf0[2];
      #pragma unroll
      for (int m = 0; m < 8; ++m)
        af[m] = *(const s16x8*)(Ab + (wm * 128 + m * 16 + q) * 64 + so);
      #pragma unroll
      for (int n = 0; n < 2; ++n)
        bf0[n] = *(const s16x8*)(Bb + (wn * 64 + n * 16 + q) * 64 + so);
      if (pre) stage2(cur ^ 1, t + 1, ks * 2);
      asm volatile("s_waitcnt lgkmcnt(0)" ::: "memory");
      __builtin_amdgcn_sched_barrier(0);
      __builtin_amdgcn_s_setprio(1);
      #pragma unroll
      for (int m = 0; m < 8; ++m) {
        acc[m][0] = __builtin_amdgcn_mfma_f32_16x16x32_bf16(af[m], bf0[0], acc[m][0], 0, 0, 0);
        acc[m][1] = __builtin_amdgcn_mfma_f32_16x16x32_bf16(af[m], bf0[1], acc[m][1], 0, 0, 0);
      }
      __builtin_amdgcn_s_setprio(0);
      // sub-phase nh=1 (N-frags 2,3; reuses af)
      s16x8 bf1[2];
      #pragma unroll
      for (int n = 0; n < 2; ++n)
        bf1[n] = *(const s16x8*)(Bb + (wn * 64 + (2 + n) * 16 + q) * 64 + so);
      if (pre) stage2(cur ^ 1, t + 1, ks * 2 + 1);
      asm volatile("s_waitcnt lgkmcnt(0)" ::: "memory");
      __builtin_amdgcn_sched_barrier(0);
      __builtin_amdgcn_s_setprio(1);
      #pragma unroll
      for (int m = 0; m < 8; ++m) {
        acc[m][2] = __builtin_amdgcn_mfma_f32_16x16x32_bf16(af[m], bf1[0], acc[m][2], 0, 0, 0);
        acc[m][3] = __builtin_amdgcn_mfma_f32_16x16x32_bf16(af[m], bf1[1], acc[m][3], 0, 0, 0);
      }
      __builtin_amdgcn_s_setprio(0);
    }
    cur ^= 1;
  }

  #pragma unroll
  for (int m = 0; m < 8; ++m) {
    const int row0 = bm * 256 + wm * 128 + m * 16 + g * 4;
    #pragma unroll
    for (int n = 0; n < 4; ++n) {
      const int col = bn * 256 + wn * 64 + n * 16 + q;
      float bv = 0.0f;
      if (BIAS) bv = bias[col];
      #pragma unroll
      for (int r = 0; r < 4; ++r) {
        const size_t idx = (size_t)(row0 + r) * N + col;
        float v = acc[m][n][r] + bv;
        if (RES)  v += resid[idx];
        if (SILU) v = v / (1.0f + __expf(-v));
        if (OF32) Cf[idx] = v;
        if (OBF)  Cb[idx] = f2bf(v);
      }
    }
  }
}

// ---------------- Flash attention (Q-tile 32 rows/wave: 2x LDS-read reuse) ----------------
// Block = 8 waves x 32 q-rows = 256 rows; grid = 32 bh x 8 qt = 256 (1 block/CU).
// Each kf LDS read feeds 2 QK MFMAs; each V tr-read pair feeds 2 PV MFMAs —
// halves the DS-pipe issue per MFMA (the measured limiter). 3-slot rotating
// KV LDS, counted vmcnt(2) + one raw barrier per KV tile, static softmax.
__global__ __launch_bounds__(512, 2) void attn_k(
    const u16* __restrict__ Q, const u16* __restrict__ KV, u16* __restrict__ O)
{
  __shared__ u16 Ks[3][64 * 64];
  __shared__ u16 Vs[3][64 * 64];
  const int tid = threadIdx.x;
  const int w = tid >> 6, l = tid & 63;
  const int g = l >> 4, q = l & 15;
  // XCD-clustered mapping: xcd = blk&7 owns bh = xcd*4..xcd*4+3
  const int idx = blockIdx.x >> 3;          // 0..31
  const int bh = (blockIdx.x & 7) * 4 + (idx >> 3);
  const int qt = idx & 7;
  const int b = bh >> 4, h = bh & 15;

  // Q fragments: 2 groups of 16 rows (j=0,1); pre-scaled by LOG2E/8 at cast
  s16x8 qf[2][2];
  #pragma unroll
  for (int j = 0; j < 2; ++j) {
    const size_t qrow = (size_t)(b * 2048 + qt * 256 + w * 32 + j * 16 + q);
    qf[j][0] = *(const s16x8*)&Q[qrow * 1024 + h * 64 + g * 8];
    qf[j][1] = *(const s16x8*)&Q[qrow * 1024 + h * 64 + 32 + g * 8];
  }

  f32x4 oacc[2][4] = {};
  f32x4 ls0 = {0.0f, 0.0f, 0.0f, 0.0f};
  f32x4 ls1 = {0.0f, 0.0f, 0.0f, 0.0f};

  const u16* kvb = KV + (size_t)b * 2048 * 2048;
  const unsigned vs_base =
      (unsigned)(unsigned long long)(__attribute__((address_space(3))) u16*)Vs;

  auto stage = [&](int buf, int kv0) {
    const int c = tid;
    const int krow = c >> 3, slot = c & 7;
    gload16(kvb + (size_t)(kv0 + krow) * 2048 + h * 64 + ((slot ^ (krow & 7)) << 3),
            &Ks[buf][(size_t)(w << 6) * 8]);
    const int vkv = ((c >> 3) & 15) * 4 + ((c >> 1) & 3);
    const int vd0 = ((c >> 7) & 3) * 16 + (c & 1) * 8;
    gload16(kvb + (size_t)(kv0 + vkv) * 2048 + 1024 + h * 64 + vd0,
            &Vs[buf][(size_t)(w << 6) * 8]);
  };

  stage(0, 0);
  stage(1, 64);
  int cur = 0;

  for (int kt = 0; kt < 32; ++kt) {
    if (kt < 31) asm volatile("s_waitcnt vmcnt(2)" ::: "memory");
    else         asm volatile("s_waitcnt vmcnt(0)" ::: "memory");
    __builtin_amdgcn_s_barrier();
    asm volatile("" ::: "memory");
    if (kt + 2 < 32) stage((cur == 0) ? 2 : cur - 1, (kt + 2) * 64);

    // S^T = K @ Q^T: sacc[j][nf] reg r = S^T[k = nf*16+g*4+r][qrow j*16+q]
    const char* ksb = (const char*)Ks[cur];
    f32x4 sacc[2][4] = {};
    __builtin_amdgcn_s_setprio(1);
    #pragma unroll
    for (int s = 0; s < 2; ++s)
      #pragma unroll
      for (int nf = 0; nf < 4; ++nf) {
        const int krw = nf * 16 + q;
        const s16x8 kf = *(const s16x8*)(ksb + krw * 128 +
                              ((s * 64 + g * 16) ^ ((krw & 7) << 4)));
        sacc[0][nf] = __builtin_amdgcn_mfma_f32_16x16x32_bf16(kf, qf[0][s], sacc[0][nf], 0, 0, 0);
        sacc[1][nf] = __builtin_amdgcn_mfma_f32_16x16x32_bf16(kf, qf[1][s], sacc[1][nf], 0, 0, 0);
      }
    __builtin_amdgcn_s_setprio(0);

    // static softmax: P = exp2(S'); accumulate l vectors (reduce at end)
    #pragma unroll
    for (int j = 0; j < 2; ++j)
      #pragma unroll
      for (int nf = 0; nf < 4; ++nf)
        #pragma unroll
        for (int r = 0; r < 4; ++r)
          sacc[j][nf][r] = __builtin_amdgcn_exp2f(sacc[j][nf][r]);
    ls0 += sacc[0][0]; ls0 += sacc[0][1]; ls0 += sacc[0][2]; ls0 += sacc[0][3];
    ls1 += sacc[1][0]; ls1 += sacc[1][1]; ls1 += sacc[1][2]; ls1 += sacc[1][3];

    // PA fragments (lane-local repack of sacc)
    union { u32x4 u; s16x8 s8; } au[2][2];
    #pragma unroll
    for (int j = 0; j < 2; ++j)
      #pragma unroll
      for (int s = 0; s < 2; ++s) {
        au[j][s].u[0] = cvtpk(sacc[j][2*s  ][0], sacc[j][2*s  ][1]);
        au[j][s].u[1] = cvtpk(sacc[j][2*s  ][2], sacc[j][2*s  ][3]);
        au[j][s].u[2] = cvtpk(sacc[j][2*s+1][0], sacc[j][2*s+1][1]);
        au[j][s].u[3] = cvtpk(sacc[j][2*s+1][2], sacc[j][2*s+1][3]);
      }

    // all 16 V tr-reads + single wait, one asm block (safe batched form).
    const unsigned a0 = vs_base + (unsigned)(cur * 8192) + (unsigned)(g * 128 + 2 * q);
    u32x2 v0,v1,v2,v3,v4,v5,v6,v7,v8,v9,v10,v11,v12,v13,v14,v15;
    asm volatile(
        "ds_read_b64_tr_b16 %0,  %16\n\t"
        "ds_read_b64_tr_b16 %1,  %16 offset:512\n\t"
        "ds_read_b64_tr_b16 %2,  %16 offset:2048\n\t"
        "ds_read_b64_tr_b16 %3,  %16 offset:2560\n\t"
        "ds_read_b64_tr_b16 %4,  %16 offset:4096\n\t"
        "ds_read_b64_tr_b16 %5,  %16 offset:4608\n\t"
        "ds_read_b64_tr_b16 %6,  %16 offset:6144\n\t"
        "ds_read_b64_tr_b16 %7,  %16 offset:6656\n\t"
        "ds_read_b64_tr_b16 %8,  %16 offset:1024\n\t"
        "ds_read_b64_tr_b16 %9,  %16 offset:1536\n\t"
        "ds_read_b64_tr_b16 %10, %16 offset:3072\n\t"
        "ds_read_b64_tr_b16 %11, %16 offset:3584\n\t"
        "ds_read_b64_tr_b16 %12, %16 offset:5120\n\t"
        "ds_read_b64_tr_b16 %13, %16 offset:5632\n\t"
        "ds_read_b64_tr_b16 %14, %16 offset:7168\n\t"
        "ds_read_b64_tr_b16 %15, %16 offset:7680\n\t"
        "s_waitcnt lgkmcnt(0)"
        : "=&v"(v0), "=&v"(v1), "=&v"(v2),  "=&v"(v3),
          "=&v"(v4), "=&v"(v5), "=&v"(v6),  "=&v"(v7),
          "=&v"(v8), "=&v"(v9), "=&v"(v10), "=&v"(v11),
          "=&v"(v12),"=&v"(v13),"=&v"(v14), "=&v"(v15)
        : "v"(a0) : "memory");
    __builtin_amdgcn_sched_barrier(0);

    __builtin_amdgcn_s_setprio(1);
    {
      union { u32x4 u; s16x8 s8; } bu;
      #define PVMM(nf) \
        oacc[0][nf] = __builtin_amdgcn_mfma_f32_16x16x32_bf16(au[0][S_].s8, bu.s8, oacc[0][nf], 0, 0, 0); \
        oacc[1][nf] = __builtin_amdgcn_mfma_f32_16x16x32_bf16(au[1][S_].s8, bu.s8, oacc[1][nf], 0, 0, 0);
      {
        const int S_ = 0;
        bu.u[0]=v0[0];  bu.u[1]=v0[1];  bu.u[2]=v1[0];  bu.u[3]=v1[1];  PVMM(0)
        bu.u[0]=v2[0];  bu.u[1]=v2[1];  bu.u[2]=v3[0];  bu.u[3]=v3[1];  PVMM(1)
        bu.u[0]=v4[0];  bu.u[1]=v4[1];  bu.u[2]=v5[0];  bu.u[3]=v5[1];  PVMM(2)
        bu.u[0]=v6[0];  bu.u[1]=v6[1];  bu.u[2]=v7[0];  bu.u[3]=v7[1];  PVMM(3)
      }
      {
        const int S_ = 1;
        bu.u[0]=v8[0];  bu.u[1]=v8[1];  bu.u[2]=v9[0];  bu.u[3]=v9[1];  PVMM(0)
        bu.u[0]=v10[0]; bu.u[1]=v10[1]; bu.u[2]=v11[0]; bu.u[3]=v11[1]; PVMM(1)
        bu.u[0]=v12[0]; bu.u[1]=v12[1]; bu.u[2]=v13[0]; bu.u[3]=v13[1]; PVMM(2)
        bu.u[0]=v14[0]; bu.u[1]=v14[1]; bu.u[2]=v15[0]; bu.u[3]=v15[1]; PVMM(3)
      }
      #undef PVMM
    }
    __builtin_amdgcn_s_setprio(0);

    cur = (cur == 2) ? 0 : cur + 1;
  }

  // deferred l-reduction per group, then per-row broadcast
  float lsum0 = (ls0[0] + ls0[1]) + (ls0[2] + ls0[3]);
  float lsum1 = (ls1[0] + ls1[1]) + (ls1[2] + ls1[3]);
  lsum0 += __shfl_xor(lsum0, 16);  lsum0 += __shfl_xor(lsum0, 32);
  lsum1 += __shfl_xor(lsum1, 16);  lsum1 += __shfl_xor(lsum1, 32);
  #pragma unroll
  for (int j = 0; j < 2; ++j) {
    float lr[4];
    #pragma unroll
    for (int r = 0; r < 4; ++r)
      lr[r] = __shfl(j ? lsum1 : lsum0, g * 4 + r);
    const size_t ob = (size_t)(b * 2048 + qt * 256 + w * 32 + j * 16) * 1024 + h * 64;
    #pragma unroll
    for (int r = 0; r < 4; ++r) {
      const float inv = 1.0f / lr[r];
      #pragma unroll
      for (int nf = 0; nf < 4; ++nf)
        O[ob + (size_t)(g * 4 + r) * 1024 + nf * 16 + q] = f2bf(oacc[j][nf][r] * inv);
    }
  }
}

// ---------------- launch ----------------
extern "C" void kernel_launch(void* const* d_in, const int* in_sizes, int n_in,
                              void* d_out, int out_size, void* d_ws, size_t ws_size,
                              hipStream_t stream)
{
  const float* q_x  = (const float*)d_in[0];
  const float* kv_x = (const float*)d_in[1];
  const float* Wq   = (const float*)d_in[2];
  const float* Wkv  = (const float*)d_in[3];
  const float* Wo   = (const float*)d_in[4];
  const float* bo   = (const float*)d_in[5];
  const float* lnqg = (const float*)d_in[6];
  const float* lnqb = (const float*)d_in[7];
  const float* lnkg = (const float*)d_in[8];
  const float* lnkb = (const float*)d_in[9];
  const float* W1   = (const float*)d_in[10];
  const float* b1   = (const float*)d_in[11];
  const float* W2   = (const float*)d_in[12];
  const float* b2   = (const float*)d_in[13];
  float* out = (float*)d_out;

  char* ws = (char*)d_ws;
  const size_t MB = 1024 * 1024;
  u16*   wq_b  = (u16*)  (ws +  0 * MB);   // 2 MB
  u16*   wkv_b = (u16*)  (ws +  2 * MB);   // 4 MB
  u16*   wo_b  = (u16*)  (ws +  6 * MB);   // 2 MB
  u16*   w1_b  = (u16*)  (ws +  8 * MB);   // 8 MB
  u16*   w2_b  = (u16*)  (ws + 16 * MB);   // 8 MB
  u16*   lnq   = (u16*)  (ws + 24 * MB);   // 8 MB
  u16*   lnk   = (u16*)  (ws + 32 * MB);   // 8 MB
  u16*   qp    = (u16*)  (ws + 40 * MB);   // 8 MB
  u16*   kvp   = (u16*)  (ws + 48 * MB);   // 16 MB
  u16*   ao    = (u16*)  (ws + 64 * MB);   // 8 MB
  float* xf    = (float*)(ws + 72 * MB);   // 16 MB
  u16*   xb    = (u16*)  (ws + 88 * MB);   // 8 MB
  u16*   hb    = (u16*)  (ws + 96 * MB);   // 32 MB -> 128 MB total

  prep_k<<<dim3(20480), dim3(256), 0, stream>>>(
      Wq, Wkv, Wo, W1, W2, wq_b, wkv_b, wo_b, w1_b, w2_b,
      q_x, kv_x, lnqg, lnqb, lnkg, lnkb, lnq, lnk);

  // q = LN(q_x) @ (Wq*LOG2E/8)^T ; kv = LN(kv_x) @ Wkv^T (merged, 2-buf body)
  gemm_qkv_k<<<dim3(1536), dim3(512), 0, stream>>>(lnq, wq_b, qp, lnk, wkv_b, kvp);
  // flash attention (Q-tile 256/block, 32 rows/wave)
  attn_k<<<dim3(256), dim3(512), 0, stream>>>(qp, kvp, ao);
  // x = q_x + ao @ Wo^T + bo   (2-buf body, 3 blocks/CU)
  gemm_k2<1,1,0,1,1><<<dim3(512),  dim3(512), 0, stream>>>(
      ao, wo_b, xb, xf, bo, q_x, 1024, 1024);
  // h = silu(x @ W1^T + b1)   (256^2 phase-pipelined)
  gemm256_k<1,0,1,0,1><<<dim3(256), dim3(512), 0, stream>>>(
      xb, w1_b, hb, nullptr, b1, nullptr, 4096, 1024);
  // out = x + h @ W2^T + b2    (3-slot counted-vmcnt body, K=4096)
  gemm_k3<1,1,0,1,0><<<dim3(512),  dim3(512), 0, stream>>>(
      hb, w2_b, nullptr, out, b2, xf, 1024, 4096);
}

// Round 16
// 194.695 us; speedup vs baseline: 1.0256x; 1.0256x over previous
//
#include <hip/hip_runtime.h>

using u16   = unsigned short;
using f32x4 = __attribute__((ext_vector_type(4))) float;
using s16x8 = __attribute__((ext_vector_type(8))) short;
using u32x2 = __attribute__((ext_vector_type(2))) unsigned int;
using u32x4 = __attribute__((ext_vector_type(4))) unsigned int;

#define LOG2E 1.44269504088896f

static __device__ __forceinline__ u16 f2bf(float f) {
  union { float f; unsigned u; } a; a.f = f;
  unsigned r = a.u + 0x7fffu + ((a.u >> 16) & 1u);
  return (u16)(r >> 16);
}
// pack two f32 -> u32 of 2 bf16 (lo = first arg), RNE
static __device__ __forceinline__ unsigned cvtpk(float lo, float hi) {
  unsigned r;
  asm("v_cvt_pk_bf16_f32 %0, %1, %2" : "=v"(r) : "v"(lo), "v"(hi));
  return r;
}

// global(16B per lane, per-lane src addr) -> LDS (wave-uniform base + lane*16)
static __device__ __forceinline__ void gload16(const void* g, void* l) {
  __builtin_amdgcn_global_load_lds(
      (__attribute__((address_space(1))) unsigned int*)g,
      (__attribute__((address_space(3))) unsigned int*)l, 16, 0, 0);
}

// bijective XCD swizzle for nb % 8 == 0
static __device__ __forceinline__ int xcd_swz(int b, int nb) {
  return (b & 7) * (nb >> 3) + (b >> 3);
}

// ---------------- merged prep: weight casts + 2x LayerNorm ----------------
__global__ __launch_bounds__(256) void prep_k(
    const float* __restrict__ Wq, const float* __restrict__ Wkv,
    const float* __restrict__ Wo, const float* __restrict__ W1,
    const float* __restrict__ W2,
    u16* __restrict__ wq_b, u16* __restrict__ wkv_b, u16* __restrict__ wo_b,
    u16* __restrict__ w1_b, u16* __restrict__ w2_b,
    const float* __restrict__ xq, const float* __restrict__ xk,
    const float* __restrict__ gq, const float* __restrict__ bq,
    const float* __restrict__ gk, const float* __restrict__ bk,
    u16* __restrict__ oq, u16* __restrict__ ok)
{
  const int blk = blockIdx.x, t = threadIdx.x;
  if (blk < 12288) {
    const int i = blk * 256 + t;   // float4-chunk id
    const float* src; u16* dst; int off; float sc = 1.0f;
    if      (i <  262144) { src = Wq;  dst = wq_b;  off = i; sc = 0.125f * LOG2E; }
    else if (i <  786432) { src = Wkv; dst = wkv_b; off = i -  262144; }
    else if (i < 1048576) { src = Wo;  dst = wo_b;  off = i -  786432; }
    else if (i < 2097152) { src = W1;  dst = w1_b;  off = i - 1048576; }
    else                  { src = W2;  dst = w2_b;  off = i - 2097152; }
    const float4 v = ((const float4*)src)[off];
    ushort4 o;
    o.x = f2bf(v.x * sc); o.y = f2bf(v.y * sc); o.z = f2bf(v.z * sc); o.w = f2bf(v.w * sc);
    ((ushort4*)dst)[off] = o;
    return;
  }
  int row = blk - 12288;
  const float* x; const float* gam; const float* bet; u16* out;
  if (row < 4096) { x = xq; gam = gq; bet = bq; out = oq; }
  else { row -= 4096; x = xk; gam = gk; bet = bk; out = ok; }
  const float4 v = ((const float4*)(x + (size_t)row * 1024))[t];
  float s  = v.x + v.y + v.z + v.w;
  float ss = v.x*v.x + v.y*v.y + v.z*v.z + v.w*v.w;
  #pragma unroll
  for (int m = 1; m < 64; m <<= 1) { s += __shfl_xor(s, m); ss += __shfl_xor(ss, m); }
  __shared__ float red[8];
  const int w = t >> 6;
  if ((t & 63) == 0) { red[w] = s; red[4 + w] = ss; }
  __syncthreads();
  s  = red[0] + red[1] + red[2] + red[3];
  ss = red[4] + red[5] + red[6] + red[7];
  const float mu   = s * (1.0f / 1024.0f);
  const float rstd = rsqrtf(ss * (1.0f / 1024.0f) - mu * mu + 1e-5f);
  const float4 gv = ((const float4*)gam)[t];
  const float4 bv = ((const float4*)bet)[t];
  ushort4 o;
  o.x = f2bf((v.x - mu) * rstd * gv.x + bv.x);
  o.y = f2bf((v.y - mu) * rstd * gv.y + bv.y);
  o.z = f2bf((v.z - mu) * rstd * gv.z + bv.z);
  o.w = f2bf((v.w - mu) * rstd * gv.w + bv.w);
  ((ushort4*)(out + (size_t)row * 1024))[t] = o;
}

// ======== GEMM 128x64, 2-buf 48KB LDS (for K=1024 GEMMs: 3 blocks/CU) ========
template<int BIAS, int RES, int SILU, int OF32, int OBF>
static __device__ __forceinline__ void gemm_body64_2buf(
    const u16* __restrict__ A, const u16* __restrict__ B,
    u16* __restrict__ Cb, float* __restrict__ Cf,
    const float* __restrict__ bias, const float* __restrict__ resid,
    int N, int K, int bid, u16* smem)
{
  const int tid = threadIdx.x;
  const int w = tid >> 6, l = tid & 63;
  const int g = l >> 4, q = l & 15;
  const int ntn = N >> 6;
  const int bm = bid / ntn, bn = bid - bm * ntn;
  const int wr = w >> 1, wc = w & 1;
  const int sw = (q & 7) << 4;
  f32x4 acc[2][2] = {};

  const size_t abase = (size_t)(bm * 128) * K;
  const size_t bbase = (size_t)(bn * 64) * K;

  auto stage = [&](int buf, int k0) {
    u16* as = smem + buf * 8192;
    u16* bs = smem + 16384 + buf * 4096;
    #pragma unroll
    for (int r = 0; r < 2; ++r) {
      const int c = (r << 9) + tid;            // A chunk 0..1023 (16B each)
      const int row = c >> 3;
      const int sp = (c & 7) ^ (row & 7);      // inverse-swizzled source part
      gload16(A + abase + (size_t)row * K + k0 + sp * 8,
              as + (size_t)((r << 9) + (w << 6)) * 8);
    }
    const int row = tid >> 3;                  // B chunk 0..511
    const int sp = (tid & 7) ^ (row & 7);
    gload16(B + bbase + (size_t)row * K + k0 + sp * 8,
            bs + (size_t)(w << 6) * 8);
  };

  const int NT = K >> 6;
  stage(0, 0);
  asm volatile("s_waitcnt vmcnt(0)" ::: "memory");
  __syncthreads();
  int cur = 0;
  for (int t = 0; t < NT; ++t) {
    if (t + 1 < NT) stage(cur ^ 1, (t + 1) << 6);
    const char* as = (const char*)(smem + cur * 8192);
    const char* bs = (const char*)(smem + 16384 + cur * 4096);
    #pragma unroll
    for (int ks = 0; ks < 2; ++ks) {
      s16x8 af[2], bfr[2];
      #pragma unroll
      for (int m = 0; m < 2; ++m)
        af[m] = *(const s16x8*)(as + (size_t)(wr * 32 + m * 16 + q) * 128 +
                                ((ks * 64 + g * 16) ^ sw));
      #pragma unroll
      for (int n = 0; n < 2; ++n)
        bfr[n] = *(const s16x8*)(bs + (size_t)(wc * 32 + n * 16 + q) * 128 +
                                 ((ks * 64 + g * 16) ^ sw));
      #pragma unroll
      for (int m = 0; m < 2; ++m)
        #pragma unroll
        for (int n = 0; n < 2; ++n)
          acc[m][n] = __builtin_amdgcn_mfma_f32_16x16x32_bf16(af[m], bfr[n], acc[m][n], 0, 0, 0);
    }
    asm volatile("s_waitcnt vmcnt(0)" ::: "memory");
    __syncthreads();
    cur ^= 1;
  }

  #pragma unroll
  for (int m = 0; m < 2; ++m) {
    const int row0 = bm * 128 + wr * 32 + m * 16 + g * 4;
    #pragma unroll
    for (int n = 0; n < 2; ++n) {
      const int col = bn * 64 + wc * 32 + n * 16 + q;
      float bv = 0.0f;
      if (BIAS) bv = bias[col];
      #pragma unroll
      for (int r = 0; r < 4; ++r) {
        const size_t idx = (size_t)(row0 + r) * N + col;
        float v = acc[m][n][r] + bv;
        if (RES)  v += resid[idx];
        if (SILU) v = v / (1.0f + __expf(-v));
        if (OF32) Cf[idx] = v;
        if (OBF)  Cb[idx] = f2bf(v);
      }
    }
  }
}

template<int BIAS, int RES, int SILU, int OF32, int OBF>
__global__ __launch_bounds__(512, 4) void gemm_k2(
    const u16* __restrict__ A, const u16* __restrict__ B,
    u16* __restrict__ Cb, float* __restrict__ Cf,
    const float* __restrict__ bias, const float* __restrict__ resid,
    int N, int K)
{
  __shared__ u16 smem[24576];
  const int bid = xcd_swz(blockIdx.x, gridDim.x);
  gemm_body64_2buf<BIAS, RES, SILU, OF32, OBF>(A, B, Cb, Cf, bias, resid, N, K, bid, smem);
}

// q-proj (512 tiles) and kv-proj (1024 tiles) merged; 3 blocks/CU co-resident
__global__ __launch_bounds__(512, 4) void gemm_qkv_k(
    const u16* __restrict__ lnq, const u16* __restrict__ wq, u16* __restrict__ qp,
    const u16* __restrict__ lnk, const u16* __restrict__ wkv, u16* __restrict__ kvp)
{
  __shared__ u16 smem[24576];
  const int sbid = xcd_swz(blockIdx.x, 1536);
  if (sbid < 512)
    gemm_body64_2buf<0,0,0,0,1>(lnq, wq, qp, nullptr, nullptr, nullptr, 1024, 1024,
                                sbid, smem);
  else
    gemm_body64_2buf<0,0,0,0,1>(lnk, wkv, kvp, nullptr, nullptr, nullptr, 2048, 1024,
                                sbid - 512, smem);
}

// ======== GEMM 128x64, 3-slot rotating LDS, counted vmcnt (for w2, K=4096) ========
template<int BIAS, int RES, int SILU, int OF32, int OBF>
__global__ __launch_bounds__(512, 4) void gemm_k3(
    const u16* __restrict__ A, const u16* __restrict__ B,
    u16* __restrict__ Cb, float* __restrict__ Cf,
    const float* __restrict__ bias, const float* __restrict__ resid,
    int N, int K)
{
  __shared__ u16 smem[36864];
  const int bid = xcd_swz(blockIdx.x, gridDim.x);
  const int tid = threadIdx.x;
  const int w = tid >> 6, l = tid & 63;
  const int g = l >> 4, q = l & 15;
  const int ntn = N >> 6;
  const int bm = bid / ntn, bn = bid - bm * ntn;
  const int wr = w >> 1, wc = w & 1;
  const int sw = (q & 7) << 4;
  f32x4 acc[2][2] = {};

  const size_t abase = (size_t)(bm * 128) * K;
  const size_t bbase = (size_t)(bn * 64) * K;

  auto stage = [&](int buf, int k0) {
    u16* as = smem + buf * 8192;
    u16* bs = smem + 24576 + buf * 4096;
    #pragma unroll
    for (int r = 0; r < 2; ++r) {
      const int c = (r << 9) + tid;            // A chunk 0..1023 (16B each)
      const int row = c >> 3;
      const int sp = (c & 7) ^ (row & 7);      // inverse-swizzled source part
      gload16(A + abase + (size_t)row * K + k0 + sp * 8,
              as + (size_t)((r << 9) + (w << 6)) * 8);
    }
    const int row = tid >> 3;                  // B chunk 0..511
    const int sp = (tid & 7) ^ (row & 7);
    gload16(B + bbase + (size_t)row * K + k0 + sp * 8,
            bs + (size_t)(w << 6) * 8);
  };

  const int NT = K >> 6;
  stage(0, 0);
  stage(1, 64);
  int cur = 0;
  for (int t = 0; t < NT; ++t) {
    if (t + 1 < NT) asm volatile("s_waitcnt vmcnt(3)" ::: "memory");
    else            asm volatile("s_waitcnt vmcnt(0)" ::: "memory");
    __builtin_amdgcn_s_barrier();
    asm volatile("" ::: "memory");
    if (t + 2 < NT) stage((cur == 0) ? 2 : cur - 1, (t + 2) << 6);

    const char* as = (const char*)(smem + cur * 8192);
    const char* bs = (const char*)(smem + 24576 + cur * 4096);
    #pragma unroll
    for (int ks = 0; ks < 2; ++ks) {
      s16x8 af[2], bfr[2];
      #pragma unroll
      for (int m = 0; m < 2; ++m)
        af[m] = *(const s16x8*)(as + (size_t)(wr * 32 + m * 16 + q) * 128 +
                                ((ks * 64 + g * 16) ^ sw));
      #pragma unroll
      for (int n = 0; n < 2; ++n)
        bfr[n] = *(const s16x8*)(bs + (size_t)(wc * 32 + n * 16 + q) * 128 +
                                 ((ks * 64 + g * 16) ^ sw));
      __builtin_amdgcn_s_setprio(1);
      #pragma unroll
      for (int m = 0; m < 2; ++m)
        #pragma unroll
        for (int n = 0; n < 2; ++n)
          acc[m][n] = __builtin_amdgcn_mfma_f32_16x16x32_bf16(af[m], bfr[n], acc[m][n], 0, 0, 0);
      __builtin_amdgcn_s_setprio(0);
    }
    cur = (cur == 2) ? 0 : cur + 1;
  }

  #pragma unroll
  for (int m = 0; m < 2; ++m) {
    const int row0 = bm * 128 + wr * 32 + m * 16 + g * 4;
    #pragma unroll
    for (int n = 0; n < 2; ++n) {
      const int col = bn * 64 + wc * 32 + n * 16 + q;
      float bv = 0.0f;
      if (BIAS) bv = bias[col];
      #pragma unroll
      for (int r = 0; r < 4; ++r) {
        const size_t idx = (size_t)(row0 + r) * N + col;
        float v = acc[m][n][r] + bv;
        if (RES)  v += resid[idx];
        if (SILU) v = v / (1.0f + __expf(-v));
        if (OF32) Cf[idx] = v;
        if (OBF)  Cb[idx] = f2bf(v);
      }
    }
  }
}

// ---------------- GEMM 256x256, BK=64, phase schedule (w1) ----------------
template<int BIAS, int RES, int SILU, int OF32, int OBF>
__global__ __launch_bounds__(512, 2) void gemm256_k(
    const u16* __restrict__ A, const u16* __restrict__ B,
    u16* __restrict__ Cb, float* __restrict__ Cf,
    const float* __restrict__ bias, const float* __restrict__ resid,
    int N, int K)
{
  __shared__ u16 smem[65536];          // 128 KB
  char* smem_c = (char*)smem;
  const int tid = threadIdx.x;
  const int w = tid >> 6, l = tid & 63;
  const int g = l >> 4, q = l & 15;
  const int wm = w >> 2, wn = w & 3;
  const int ntn = N >> 8;
  const int bid = xcd_swz(blockIdx.x, gridDim.x);
  const int bm = bid / ntn, bn = bid - bm * ntn;

  const size_t abase = (size_t)(bm * 256) * K;
  const size_t bbase = (size_t)(bn * 256) * K;

  f32x4 acc[8][4] = {};

  // part: 0=Ak0 1=Bk0 2=Ak1 3=Bk1 ; 2 loads/thread
  auto stage2 = [&](int buf, int kt, int part) {
    const int isB = part & 1, khalf = part >> 1;
    #pragma unroll
    for (int sub = 0; sub < 2; ++sub) {
      const int row  = sub * 128 + (tid >> 2);
      const int slot = (tid & 3) ^ ((row >> 1) & 3);
      const u16* src = (isB ? B + bbase : A + abase)
                     + (size_t)row * K + kt * 64 + khalf * 32 + slot * 8;
      char* dst = smem_c + buf * 65536 + isB * 32768 + khalf * 16384
                + sub * 8192 + w * 1024;   // wave-uniform; HW adds lane*16
      gload16(src, dst);
    }
  };

  const int NT = K >> 6;
  stage2(0, 0, 0); stage2(0, 0, 1); stage2(0, 0, 2); stage2(0, 0, 3);
  int cur = 0;
  const int so = (g ^ ((q >> 1) & 3)) * 16;
  for (int t = 0; t < NT; ++t) {
    const bool pre = (t + 1 < NT);
    const char* base = smem_c + cur * 65536;
    #pragma unroll
    for (int ks = 0; ks < 2; ++ks) {
      if (ks == 0 || pre) asm volatile("s_waitcnt vmcnt(4)" ::: "memory");
      else                asm volatile("s_waitcnt vmcnt(0)" ::: "memory");
      asm volatile("" ::: "memory");
      __builtin_amdgcn_s_barrier();
      asm volatile("" ::: "memory");
      const char* Ab = base + ks * 16384;
      const char* Bb = base + 32768 + ks * 16384;
      s16x8 af[8], bf0[2];
      #pragma unroll
      for (int m = 0; m < 8; ++m)
        af[m] = *(const s16x8*)(Ab + (wm * 128 + m * 16 + q) * 64 + so);
      #pragma unroll
      for (int n = 0; n < 2; ++n)
        bf0[n] = *(const s16x8*)(Bb + (wn * 64 + n * 16 + q) * 64 + so);
      if (pre) stage2(cur ^ 1, t + 1, ks * 2);
      asm volatile("s_waitcnt lgkmcnt(0)" ::: "memory");
      __builtin_amdgcn_sched_barrier(0);
      __builtin_amdgcn_s_setprio(1);
      #pragma unroll
      for (int m = 0; m < 8; ++m) {
        acc[m][0] = __builtin_amdgcn_mfma_f32_16x16x32_bf16(af[m], bf0[0], acc[m][0], 0, 0, 0);
        acc[m][1] = __builtin_amdgcn_mfma_f32_16x16x32_bf16(af[m], bf0[1], acc[m][1], 0, 0, 0);
      }
      __builtin_amdgcn_s_setprio(0);
      // sub-phase nh=1 (N-frags 2,3; reuses af)
      s16x8 bf1[2];
      #pragma unroll
      for (int n = 0; n < 2; ++n)
        bf1[n] = *(const s16x8*)(Bb + (wn * 64 + (2 + n) * 16 + q) * 64 + so);
      if (pre) stage2(cur ^ 1, t + 1, ks * 2 + 1);
      asm volatile("s_waitcnt lgkmcnt(0)" ::: "memory");
      __builtin_amdgcn_sched_barrier(0);
      __builtin_amdgcn_s_setprio(1);
      #pragma unroll
      for (int m = 0; m < 8; ++m) {
        acc[m][2] = __builtin_amdgcn_mfma_f32_16x16x32_bf16(af[m], bf1[0], acc[m][2], 0, 0, 0);
        acc[m][3] = __builtin_amdgcn_mfma_f32_16x16x32_bf16(af[m], bf1[1], acc[m][3], 0, 0, 0);
      }
      __builtin_amdgcn_s_setprio(0);
    }
    cur ^= 1;
  }

  #pragma unroll
  for (int m = 0; m < 8; ++m) {
    const int row0 = bm * 256 + wm * 128 + m * 16 + g * 4;
    #pragma unroll
    for (int n = 0; n < 4; ++n) {
      const int col = bn * 256 + wn * 64 + n * 16 + q;
      float bv = 0.0f;
      if (BIAS) bv = bias[col];
      #pragma unroll
      for (int r = 0; r < 4; ++r) {
        const size_t idx = (size_t)(row0 + r) * N + col;
        float v = acc[m][n][r] + bv;
        if (RES)  v += resid[idx];
        if (SILU) v = v / (1.0f + __expf(-v));
        if (OF32) Cf[idx] = v;
        if (OBF)  Cb[idx] = f2bf(v);
      }
    }
  }
}

// ---------------- Flash attention ----------------
// Q-tile 128 / 8 waves, 3-slot rotating KV LDS, counted vmcnt(2) + ONE raw
// barrier per KV tile. Static softmax (P = exp2(S'), bounded inputs),
// deferred l-reduction. Grid 512 = 2 blocks/CU (TLP hides the serial chain).
__global__ __launch_bounds__(512, 4) void attn_k(
    const u16* __restrict__ Q, const u16* __restrict__ KV, u16* __restrict__ O)
{
  __shared__ u16 Ks[3][64 * 64];
  __shared__ u16 Vs[3][64 * 64];
  const int tid = threadIdx.x;
  const int w = tid >> 6, l = tid & 63;
  const int g = l >> 4, q = l & 15;
  // XCD-clustered mapping: xcd = blk&7 owns bh = xcd*4..xcd*4+3 (~3MB < L2)
  const int idx = blockIdx.x >> 3;
  const int bh = (blockIdx.x & 7) * 4 + (idx >> 4);
  const int qt = idx & 15;
  const int b = bh >> 4, h = bh & 15;

  // Q fragments (this wave's 16 rows x 64); pre-scaled by LOG2E/8 at cast
  const size_t qrow = (size_t)(b * 2048 + qt * 128 + w * 16 + q);
  s16x8 qf[2];
  qf[0] = *(const s16x8*)&Q[qrow * 1024 + h * 64 + g * 8];
  qf[1] = *(const s16x8*)&Q[qrow * 1024 + h * 64 + 32 + g * 8];

  f32x4 oacc[4] = {};
  f32x4 ls = {0.0f, 0.0f, 0.0f, 0.0f};

  const u16* kvb = KV + (size_t)b * 2048 * 2048;
  const unsigned vs_base =
      (unsigned)(unsigned long long)(__attribute__((address_space(3))) u16*)Vs;

  auto stage = [&](int buf, int kv0) {
    const int c = tid;
    const int krow = c >> 3, slot = c & 7;
    gload16(kvb + (size_t)(kv0 + krow) * 2048 + h * 64 + ((slot ^ (krow & 7)) << 3),
            &Ks[buf][(size_t)(w << 6) * 8]);
    const int vkv = ((c >> 3) & 15) * 4 + ((c >> 1) & 3);
    const int vd0 = ((c >> 7) & 3) * 16 + (c & 1) * 8;
    gload16(kvb + (size_t)(kv0 + vkv) * 2048 + 1024 + h * 64 + vd0,
            &Vs[buf][(size_t)(w << 6) * 8]);
  };

  stage(0, 0);
  stage(1, 64);
  int cur = 0;

  for (int kt = 0; kt < 32; ++kt) {
    if (kt < 31) asm volatile("s_waitcnt vmcnt(2)" ::: "memory");
    else         asm volatile("s_waitcnt vmcnt(0)" ::: "memory");
    __builtin_amdgcn_s_barrier();
    asm volatile("" ::: "memory");
    if (kt + 2 < 32) stage((cur == 0) ? 2 : cur - 1, (kt + 2) * 64);

    // S^T = K @ Q^T: sacc[nf] reg r = S^T[k = nf*16 + g*4 + r][qrow = q]
    const char* ksb = (const char*)Ks[cur];
    f32x4 sacc[4] = {};
    __builtin_amdgcn_s_setprio(1);
    #pragma unroll
    for (int s = 0; s < 2; ++s)
      #pragma unroll
      for (int nf = 0; nf < 4; ++nf) {
        const int krw = nf * 16 + q;
        const s16x8 kf = *(const s16x8*)(ksb + krw * 128 +
                              ((s * 64 + g * 16) ^ ((krw & 7) << 4)));
        sacc[nf] = __builtin_amdgcn_mfma_f32_16x16x32_bf16(kf, qf[s], sacc[nf], 0, 0, 0);
      }
    __builtin_amdgcn_s_setprio(0);

    // static softmax: P = exp2(S'); accumulate l as a vector (reduce at end)
    #pragma unroll
    for (int nf = 0; nf < 4; ++nf)
      #pragma unroll
      for (int r = 0; r < 4; ++r)
        sacc[nf][r] = __builtin_amdgcn_exp2f(sacc[nf][r]);
    ls += sacc[0]; ls += sacc[1]; ls += sacc[2]; ls += sacc[3];

    // PA fragments (lane-local repack of sacc)
    union { u32x4 u; s16x8 s8; } au[2];
    #pragma unroll
    for (int s = 0; s < 2; ++s) {
      au[s].u[0] = cvtpk(sacc[2*s  ][0], sacc[2*s  ][1]);
      au[s].u[1] = cvtpk(sacc[2*s  ][2], sacc[2*s  ][3]);
      au[s].u[2] = cvtpk(sacc[2*s+1][0], sacc[2*s+1][1]);
      au[s].u[3] = cvtpk(sacc[2*s+1][2], sacc[2*s+1][3]);
    }

    // all 16 V tr-reads + single wait, one asm block (safe batched form).
    const unsigned a0 = vs_base + (unsigned)(cur * 8192) + (unsigned)(g * 128 + 2 * q);
    u32x2 v0,v1,v2,v3,v4,v5,v6,v7,v8,v9,v10,v11,v12,v13,v14,v15;
    asm volatile(
        "ds_read_b64_tr_b16 %0,  %16\n\t"
        "ds_read_b64_tr_b16 %1,  %16 offset:512\n\t"
        "ds_read_b64_tr_b16 %2,  %16 offset:2048\n\t"
        "ds_read_b64_tr_b16 %3,  %16 offset:2560\n\t"
        "ds_read_b64_tr_b16 %4,  %16 offset:4096\n\t"
        "ds_read_b64_tr_b16 %5,  %16 offset:4608\n\t"
        "ds_read_b64_tr_b16 %6,  %16 offset:6144\n\t"
        "ds_read_b64_tr_b16 %7,  %16 offset:6656\n\t"
        "ds_read_b64_tr_b16 %8,  %16 offset:1024\n\t"
        "ds_read_b64_tr_b16 %9,  %16 offset:1536\n\t"
        "ds_read_b64_tr_b16 %10, %16 offset:3072\n\t"
        "ds_read_b64_tr_b16 %11, %16 offset:3584\n\t"
        "ds_read_b64_tr_b16 %12, %16 offset:5120\n\t"
        "ds_read_b64_tr_b16 %13, %16 offset:5632\n\t"
        "ds_read_b64_tr_b16 %14, %16 offset:7168\n\t"
        "ds_read_b64_tr_b16 %15, %16 offset:7680\n\t"
        "s_waitcnt lgkmcnt(0)"
        : "=&v"(v0), "=&v"(v1), "=&v"(v2),  "=&v"(v3),
          "=&v"(v4), "=&v"(v5), "=&v"(v6),  "=&v"(v7),
          "=&v"(v8), "=&v"(v9), "=&v"(v10), "=&v"(v11),
          "=&v"(v12),"=&v"(v13),"=&v"(v14), "=&v"(v15)
        : "v"(a0) : "memory");
    __builtin_amdgcn_sched_barrier(0);

    __builtin_amdgcn_s_setprio(1);
    {
      union { u32x4 u; s16x8 s8; } bu;
      bu.u[0]=v0[0];  bu.u[1]=v0[1];  bu.u[2]=v1[0];  bu.u[3]=v1[1];
      oacc[0] = __builtin_amdgcn_mfma_f32_16x16x32_bf16(au[0].s8, bu.s8, oacc[0], 0, 0, 0);
      bu.u[0]=v2[0];  bu.u[1]=v2[1];  bu.u[2]=v3[0];  bu.u[3]=v3[1];
      oacc[1] = __builtin_amdgcn_mfma_f32_16x16x32_bf16(au[0].s8, bu.s8, oacc[1], 0, 0, 0);
      bu.u[0]=v4[0];  bu.u[1]=v4[1];  bu.u[2]=v5[0];  bu.u[3]=v5[1];
      oacc[2] = __builtin_amdgcn_mfma_f32_16x16x32_bf16(au[0].s8, bu.s8, oacc[2], 0, 0, 0);
      bu.u[0]=v6[0];  bu.u[1]=v6[1];  bu.u[2]=v7[0];  bu.u[3]=v7[1];
      oacc[3] = __builtin_amdgcn_mfma_f32_16x16x32_bf16(au[0].s8, bu.s8, oacc[3], 0, 0, 0);
      bu.u[0]=v8[0];  bu.u[1]=v8[1];  bu.u[2]=v9[0];  bu.u[3]=v9[1];
      oacc[0] = __builtin_amdgcn_mfma_f32_16x16x32_bf16(au[1].s8, bu.s8, oacc[0], 0, 0, 0);
      bu.u[0]=v10[0]; bu.u[1]=v10[1]; bu.u[2]=v11[0]; bu.u[3]=v11[1];
      oacc[1] = __builtin_amdgcn_mfma_f32_16x16x32_bf16(au[1].s8, bu.s8, oacc[1], 0, 0, 0);
      bu.u[0]=v12[0]; bu.u[1]=v12[1]; bu.u[2]=v13[0]; bu.u[3]=v13[1];
      oacc[2] = __builtin_amdgcn_mfma_f32_16x16x32_bf16(au[1].s8, bu.s8, oacc[2], 0, 0, 0);
      bu.u[0]=v14[0]; bu.u[1]=v14[1]; bu.u[2]=v15[0]; bu.u[3]=v15[1];
      oacc[3] = __builtin_amdgcn_mfma_f32_16x16x32_bf16(au[1].s8, bu.s8, oacc[3], 0, 0, 0);
    }
    __builtin_amdgcn_s_setprio(0);

    cur = (cur == 2) ? 0 : cur + 1;
  }

  // deferred l-reduction: per-lane horizontal + cross-g (2 shfl), once
  float lsum = (ls[0] + ls[1]) + (ls[2] + ls[3]);
  lsum += __shfl_xor(lsum, 16);
  lsum += __shfl_xor(lsum, 32);
  float lr[4];
  #pragma unroll
  for (int r = 0; r < 4; ++r) lr[r] = __shfl(lsum, g * 4 + r);
  const size_t ob = (size_t)(b * 2048 + qt * 128 + w * 16) * 1024 + h * 64;
  #pragma unroll
  for (int r = 0; r < 4; ++r) {
    const float inv = 1.0f / lr[r];
    #pragma unroll
    for (int nf = 0; nf < 4; ++nf)
      O[ob + (size_t)(g * 4 + r) * 1024 + nf * 16 + q] = f2bf(oacc[nf][r] * inv);
  }
}

// ---------------- launch ----------------
extern "C" void kernel_launch(void* const* d_in, const int* in_sizes, int n_in,
                              void* d_out, int out_size, void* d_ws, size_t ws_size,
                              hipStream_t stream)
{
  const float* q_x  = (const float*)d_in[0];
  const float* kv_x = (const float*)d_in[1];
  const float* Wq   = (const float*)d_in[2];
  const float* Wkv  = (const float*)d_in[3];
  const float* Wo   = (const float*)d_in[4];
  const float* bo   = (const float*)d_in[5];
  const float* lnqg = (const float*)d_in[6];
  const float* lnqb = (const float*)d_in[7];
  const float* lnkg = (const float*)d_in[8];
  const float* lnkb = (const float*)d_in[9];
  const float* W1   = (const float*)d_in[10];
  const float* b1   = (const float*)d_in[11];
  const float* W2   = (const float*)d_in[12];
  const float* b2   = (const float*)d_in[13];
  float* out = (float*)d_out;

  char* ws = (char*)d_ws;
  const size_t MB = 1024 * 1024;
  u16*   wq_b  = (u16*)  (ws +  0 * MB);   // 2 MB
  u16*   wkv_b = (u16*)  (ws +  2 * MB);   // 4 MB
  u16*   wo_b  = (u16*)  (ws +  6 * MB);   // 2 MB
  u16*   w1_b  = (u16*)  (ws +  8 * MB);   // 8 MB
  u16*   w2_b  = (u16*)  (ws + 16 * MB);   // 8 MB
  u16*   lnq   = (u16*)  (ws + 24 * MB);   // 8 MB
  u16*   lnk   = (u16*)  (ws + 32 * MB);   // 8 MB
  u16*   qp    = (u16*)  (ws + 40 * MB);   // 8 MB
  u16*   kvp   = (u16*)  (ws + 48 * MB);   // 16 MB
  u16*   ao    = (u16*)  (ws + 64 * MB);   // 8 MB
  float* xf    = (float*)(ws + 72 * MB);   // 16 MB
  u16*   xb    = (u16*)  (ws + 88 * MB);   // 8 MB
  u16*   hb    = (u16*)  (ws + 96 * MB);   // 32 MB -> 128 MB total

  prep_k<<<dim3(20480), dim3(256), 0, stream>>>(
      Wq, Wkv, Wo, W1, W2, wq_b, wkv_b, wo_b, w1_b, w2_b,
      q_x, kv_x, lnqg, lnqb, lnkg, lnkb, lnq, lnk);

  // q = LN(q_x) @ (Wq*LOG2E/8)^T ; kv = LN(kv_x) @ Wkv^T (merged, 2-buf body)
  gemm_qkv_k<<<dim3(1536), dim3(512), 0, stream>>>(lnq, wq_b, qp, lnk, wkv_b, kvp);
  // flash attention (Q-tile 128, 8 waves)
  attn_k<<<dim3(512), dim3(512), 0, stream>>>(qp, kvp, ao);
  // x = q_x + ao @ Wo^T + bo   (2-buf body, 3 blocks/CU)
  gemm_k2<1,1,0,1,1><<<dim3(512),  dim3(512), 0, stream>>>(
      ao, wo_b, xb, xf, bo, q_x, 1024, 1024);
  // h = silu(x @ W1^T + b1)   (256^2 phase-pipelined)
  gemm256_k<1,0,1,0,1><<<dim3(256), dim3(512), 0, stream>>>(
      xb, w1_b, hb, nullptr, b1, nullptr, 4096, 1024);
  // out = x + h @ W2^T + b2    (3-slot counted-vmcnt body, K=4096)
  gemm_k3<1,1,0,1,0><<<dim3(512),  dim3(512), 0, stream>>>(
      hb, w2_b, nullptr, out, b2, xf, 1024, 4096);
}

// Round 17
// 193.610 us; speedup vs baseline: 1.0313x; 1.0056x over previous
//
#include <hip/hip_runtime.h>

using u16   = unsigned short;
using f32x4 = __attribute__((ext_vector_type(4))) float;
using s16x8 = __attribute__((ext_vector_type(8))) short;
using u32x2 = __attribute__((ext_vector_type(2))) unsigned int;
using u32x4 = __attribute__((ext_vector_type(4))) unsigned int;

#define LOG2E 1.44269504088896f

static __device__ __forceinline__ u16 f2bf(float f) {
  union { float f; unsigned u; } a; a.f = f;
  unsigned r = a.u + 0x7fffu + ((a.u >> 16) & 1u);
  return (u16)(r >> 16);
}
// pack two f32 -> u32 of 2 bf16 (lo = first arg), RNE
static __device__ __forceinline__ unsigned cvtpk(float lo, float hi) {
  unsigned r;
  asm("v_cvt_pk_bf16_f32 %0, %1, %2" : "=v"(r) : "v"(lo), "v"(hi));
  return r;
}

// global(16B per lane, per-lane src addr) -> LDS (wave-uniform base + lane*16)
static __device__ __forceinline__ void gload16(const void* g, void* l) {
  __builtin_amdgcn_global_load_lds(
      (__attribute__((address_space(1))) unsigned int*)g,
      (__attribute__((address_space(3))) unsigned int*)l, 16, 0, 0);
}

// bijective XCD swizzle for nb % 8 == 0
static __device__ __forceinline__ int xcd_swz(int b, int nb) {
  return (b & 7) * (nb >> 3) + (b >> 3);
}

// ---------------- merged prep: weight casts + 2x LayerNorm ----------------
__global__ __launch_bounds__(256) void prep_k(
    const float* __restrict__ Wq, const float* __restrict__ Wkv,
    const float* __restrict__ Wo, const float* __restrict__ W1,
    const float* __restrict__ W2,
    u16* __restrict__ wq_b, u16* __restrict__ wkv_b, u16* __restrict__ wo_b,
    u16* __restrict__ w1_b, u16* __restrict__ w2_b,
    const float* __restrict__ xq, const float* __restrict__ xk,
    const float* __restrict__ gq, const float* __restrict__ bq,
    const float* __restrict__ gk, const float* __restrict__ bk,
    u16* __restrict__ oq, u16* __restrict__ ok)
{
  const int blk = blockIdx.x, t = threadIdx.x;
  if (blk < 12288) {
    const int i = blk * 256 + t;   // float4-chunk id
    const float* src; u16* dst; int off; float sc = 1.0f;
    if      (i <  262144) { src = Wq;  dst = wq_b;  off = i; sc = 0.125f * LOG2E; }
    else if (i <  786432) { src = Wkv; dst = wkv_b; off = i -  262144; }
    else if (i < 1048576) { src = Wo;  dst = wo_b;  off = i -  786432; }
    else if (i < 2097152) { src = W1;  dst = w1_b;  off = i - 1048576; }
    else                  { src = W2;  dst = w2_b;  off = i - 2097152; }
    const float4 v = ((const float4*)src)[off];
    ushort4 o;
    o.x = f2bf(v.x * sc); o.y = f2bf(v.y * sc); o.z = f2bf(v.z * sc); o.w = f2bf(v.w * sc);
    ((ushort4*)dst)[off] = o;
    return;
  }
  int row = blk - 12288;
  const float* x; const float* gam; const float* bet; u16* out;
  if (row < 4096) { x = xq; gam = gq; bet = bq; out = oq; }
  else { row -= 4096; x = xk; gam = gk; bet = bk; out = ok; }
  const float4 v = ((const float4*)(x + (size_t)row * 1024))[t];
  float s  = v.x + v.y + v.z + v.w;
  float ss = v.x*v.x + v.y*v.y + v.z*v.z + v.w*v.w;
  #pragma unroll
  for (int m = 1; m < 64; m <<= 1) { s += __shfl_xor(s, m); ss += __shfl_xor(ss, m); }
  __shared__ float red[8];
  const int w = t >> 6;
  if ((t & 63) == 0) { red[w] = s; red[4 + w] = ss; }
  __syncthreads();
  s  = red[0] + red[1] + red[2] + red[3];
  ss = red[4] + red[5] + red[6] + red[7];
  const float mu   = s * (1.0f / 1024.0f);
  const float rstd = rsqrtf(ss * (1.0f / 1024.0f) - mu * mu + 1e-5f);
  const float4 gv = ((const float4*)gam)[t];
  const float4 bv = ((const float4*)bet)[t];
  ushort4 o;
  o.x = f2bf((v.x - mu) * rstd * gv.x + bv.x);
  o.y = f2bf((v.y - mu) * rstd * gv.y + bv.y);
  o.z = f2bf((v.z - mu) * rstd * gv.z + bv.z);
  o.w = f2bf((v.w - mu) * rstd * gv.w + bv.w);
  ((ushort4*)(out + (size_t)row * 1024))[t] = o;
}

// ======== GEMM 128x64, 2-buf 48KB LDS (for K=1024 GEMMs: 3 blocks/CU) ========
template<int BIAS, int RES, int SILU, int OF32, int OBF>
static __device__ __forceinline__ void gemm_body64_2buf(
    const u16* __restrict__ A, const u16* __restrict__ B,
    u16* __restrict__ Cb, float* __restrict__ Cf,
    const float* __restrict__ bias, const float* __restrict__ resid,
    int N, int K, int bid, u16* smem)
{
  const int tid = threadIdx.x;
  const int w = tid >> 6, l = tid & 63;
  const int g = l >> 4, q = l & 15;
  const int ntn = N >> 6;
  const int bm = bid / ntn, bn = bid - bm * ntn;
  const int wr = w >> 1, wc = w & 1;
  const int sw = (q & 7) << 4;
  f32x4 acc[2][2] = {};

  const size_t abase = (size_t)(bm * 128) * K;
  const size_t bbase = (size_t)(bn * 64) * K;

  auto stage = [&](int buf, int k0) {
    u16* as = smem + buf * 8192;
    u16* bs = smem + 16384 + buf * 4096;
    #pragma unroll
    for (int r = 0; r < 2; ++r) {
      const int c = (r << 9) + tid;            // A chunk 0..1023 (16B each)
      const int row = c >> 3;
      const int sp = (c & 7) ^ (row & 7);      // inverse-swizzled source part
      gload16(A + abase + (size_t)row * K + k0 + sp * 8,
              as + (size_t)((r << 9) + (w << 6)) * 8);
    }
    const int row = tid >> 3;                  // B chunk 0..511
    const int sp = (tid & 7) ^ (row & 7);
    gload16(B + bbase + (size_t)row * K + k0 + sp * 8,
            bs + (size_t)(w << 6) * 8);
  };

  const int NT = K >> 6;
  stage(0, 0);
  asm volatile("s_waitcnt vmcnt(0)" ::: "memory");
  __syncthreads();
  int cur = 0;
  for (int t = 0; t < NT; ++t) {
    if (t + 1 < NT) stage(cur ^ 1, (t + 1) << 6);
    const char* as = (const char*)(smem + cur * 8192);
    const char* bs = (const char*)(smem + 16384 + cur * 4096);
    #pragma unroll
    for (int ks = 0; ks < 2; ++ks) {
      s16x8 af[2], bfr[2];
      #pragma unroll
      for (int m = 0; m < 2; ++m)
        af[m] = *(const s16x8*)(as + (size_t)(wr * 32 + m * 16 + q) * 128 +
                                ((ks * 64 + g * 16) ^ sw));
      #pragma unroll
      for (int n = 0; n < 2; ++n)
        bfr[n] = *(const s16x8*)(bs + (size_t)(wc * 32 + n * 16 + q) * 128 +
                                 ((ks * 64 + g * 16) ^ sw));
      #pragma unroll
      for (int m = 0; m < 2; ++m)
        #pragma unroll
        for (int n = 0; n < 2; ++n)
          acc[m][n] = __builtin_amdgcn_mfma_f32_16x16x32_bf16(af[m], bfr[n], acc[m][n], 0, 0, 0);
    }
    asm volatile("s_waitcnt vmcnt(0)" ::: "memory");
    __syncthreads();
    cur ^= 1;
  }

  #pragma unroll
  for (int m = 0; m < 2; ++m) {
    const int row0 = bm * 128 + wr * 32 + m * 16 + g * 4;
    #pragma unroll
    for (int n = 0; n < 2; ++n) {
      const int col = bn * 64 + wc * 32 + n * 16 + q;
      float bv = 0.0f;
      if (BIAS) bv = bias[col];
      #pragma unroll
      for (int r = 0; r < 4; ++r) {
        const size_t idx = (size_t)(row0 + r) * N + col;
        float v = acc[m][n][r] + bv;
        if (RES)  v += resid[idx];
        if (SILU) v = v / (1.0f + __expf(-v));
        if (OF32) Cf[idx] = v;
        if (OBF)  Cb[idx] = f2bf(v);
      }
    }
  }
}

template<int BIAS, int RES, int SILU, int OF32, int OBF>
__global__ __launch_bounds__(512, 4) void gemm_k2(
    const u16* __restrict__ A, const u16* __restrict__ B,
    u16* __restrict__ Cb, float* __restrict__ Cf,
    const float* __restrict__ bias, const float* __restrict__ resid,
    int N, int K)
{
  __shared__ u16 smem[24576];
  const int bid = xcd_swz(blockIdx.x, gridDim.x);
  gemm_body64_2buf<BIAS, RES, SILU, OF32, OBF>(A, B, Cb, Cf, bias, resid, N, K, bid, smem);
}

// q-proj (512 tiles) and kv-proj (1024 tiles) merged; 3 blocks/CU co-resident
__global__ __launch_bounds__(512, 4) void gemm_qkv_k(
    const u16* __restrict__ lnq, const u16* __restrict__ wq, u16* __restrict__ qp,
    const u16* __restrict__ lnk, const u16* __restrict__ wkv, u16* __restrict__ kvp)
{
  __shared__ u16 smem[24576];
  const int sbid = xcd_swz(blockIdx.x, 1536);
  if (sbid < 512)
    gemm_body64_2buf<0,0,0,0,1>(lnq, wq, qp, nullptr, nullptr, nullptr, 1024, 1024,
                                sbid, smem);
  else
    gemm_body64_2buf<0,0,0,0,1>(lnk, wkv, kvp, nullptr, nullptr, nullptr, 2048, 1024,
                                sbid - 512, smem);
}

// ======== GEMM 128x64, 3-slot rotating LDS, counted vmcnt (for w2, K=4096) ========
// Hoisted staging addresses: per-thread global srcs (pa0/pa1/pb) and constant
// LDS dest offsets computed once; each stage = 3 pointer-adds + gload16.
template<int BIAS, int RES, int SILU, int OF32, int OBF>
__global__ __launch_bounds__(512, 4) void gemm_k3(
    const u16* __restrict__ A, const u16* __restrict__ B,
    u16* __restrict__ Cb, float* __restrict__ Cf,
    const float* __restrict__ bias, const float* __restrict__ resid,
    int N, int K)
{
  __shared__ u16 smem[36864];
  const int bid = xcd_swz(blockIdx.x, gridDim.x);
  const int tid = threadIdx.x;
  const int w = tid >> 6, l = tid & 63;
  const int g = l >> 4, q = l & 15;
  const int ntn = N >> 6;
  const int bm = bid / ntn, bn = bid - bm * ntn;
  const int wr = w >> 1, wc = w & 1;
  const int sw = (q & 7) << 4;
  f32x4 acc[2][2] = {};

  const size_t abase = (size_t)(bm * 128) * K;
  const size_t bbase = (size_t)(bn * 64) * K;

  // hoisted per-thread staging source pointers (tile-0 addresses)
  const u16* pa0; const u16* pa1; const u16* pb;
  {
    const int r0 = tid >> 3, s0 = (tid & 7) ^ (r0 & 7);
    pa0 = A + abase + (size_t)r0 * K + s0 * 8;
    const int c1 = 512 + tid;
    const int r1 = c1 >> 3, s1 = (c1 & 7) ^ (r1 & 7);
    pa1 = A + abase + (size_t)r1 * K + s1 * 8;
    const int rb = tid >> 3, sb = (tid & 7) ^ (rb & 7);
    pb = B + bbase + (size_t)rb * K + sb * 8;
  }
  const int wdo = w * 512;   // wave-uniform LDS dest offset (elements)

  auto stage = [&](int buf, int k0) {
    gload16(pa0 + k0, smem + buf * 8192 + wdo);
    gload16(pa1 + k0, smem + buf * 8192 + 4096 + wdo);
    gload16(pb  + k0, smem + 24576 + buf * 4096 + wdo);
  };

  const int NT = K >> 6;
  stage(0, 0);
  stage(1, 64);
  int cur = 0;
  for (int t = 0; t < NT; ++t) {
    if (t + 1 < NT) asm volatile("s_waitcnt vmcnt(3)" ::: "memory");
    else            asm volatile("s_waitcnt vmcnt(0)" ::: "memory");
    __builtin_amdgcn_s_barrier();
    asm volatile("" ::: "memory");
    if (t + 2 < NT) stage((cur == 0) ? 2 : cur - 1, (t + 2) << 6);

    const char* as = (const char*)(smem + cur * 8192);
    const char* bs = (const char*)(smem + 24576 + cur * 4096);
    #pragma unroll
    for (int ks = 0; ks < 2; ++ks) {
      s16x8 af[2], bfr[2];
      #pragma unroll
      for (int m = 0; m < 2; ++m)
        af[m] = *(const s16x8*)(as + (size_t)(wr * 32 + m * 16 + q) * 128 +
                                ((ks * 64 + g * 16) ^ sw));
      #pragma unroll
      for (int n = 0; n < 2; ++n)
        bfr[n] = *(const s16x8*)(bs + (size_t)(wc * 32 + n * 16 + q) * 128 +
                                 ((ks * 64 + g * 16) ^ sw));
      __builtin_amdgcn_s_setprio(1);
      #pragma unroll
      for (int m = 0; m < 2; ++m)
        #pragma unroll
        for (int n = 0; n < 2; ++n)
          acc[m][n] = __builtin_amdgcn_mfma_f32_16x16x32_bf16(af[m], bfr[n], acc[m][n], 0, 0, 0);
      __builtin_amdgcn_s_setprio(0);
    }
    cur = (cur == 2) ? 0 : cur + 1;
  }

  #pragma unroll
  for (int m = 0; m < 2; ++m) {
    const int row0 = bm * 128 + wr * 32 + m * 16 + g * 4;
    #pragma unroll
    for (int n = 0; n < 2; ++n) {
      const int col = bn * 64 + wc * 32 + n * 16 + q;
      float bv = 0.0f;
      if (BIAS) bv = bias[col];
      #pragma unroll
      for (int r = 0; r < 4; ++r) {
        const size_t idx = (size_t)(row0 + r) * N + col;
        float v = acc[m][n][r] + bv;
        if (RES)  v += resid[idx];
        if (SILU) v = v / (1.0f + __expf(-v));
        if (OF32) Cf[idx] = v;
        if (OBF)  Cb[idx] = f2bf(v);
      }
    }
  }
}

// ---------------- GEMM 256x256, BK=64, phase schedule (w1) ----------------
template<int BIAS, int RES, int SILU, int OF32, int OBF>
__global__ __launch_bounds__(512, 2) void gemm256_k(
    const u16* __restrict__ A, const u16* __restrict__ B,
    u16* __restrict__ Cb, float* __restrict__ Cf,
    const float* __restrict__ bias, const float* __restrict__ resid,
    int N, int K)
{
  __shared__ u16 smem[65536];          // 128 KB
  char* smem_c = (char*)smem;
  const int tid = threadIdx.x;
  const int w = tid >> 6, l = tid & 63;
  const int g = l >> 4, q = l & 15;
  const int wm = w >> 2, wn = w & 3;
  const int ntn = N >> 8;
  const int bid = xcd_swz(blockIdx.x, gridDim.x);
  const int bm = bid / ntn, bn = bid - bm * ntn;

  const size_t abase = (size_t)(bm * 256) * K;
  const size_t bbase = (size_t)(bn * 256) * K;

  f32x4 acc[8][4] = {};

  // part: 0=Ak0 1=Bk0 2=Ak1 3=Bk1 ; 2 loads/thread
  auto stage2 = [&](int buf, int kt, int part) {
    const int isB = part & 1, khalf = part >> 1;
    #pragma unroll
    for (int sub = 0; sub < 2; ++sub) {
      const int row  = sub * 128 + (tid >> 2);
      const int slot = (tid & 3) ^ ((row >> 1) & 3);
      const u16* src = (isB ? B + bbase : A + abase)
                     + (size_t)row * K + kt * 64 + khalf * 32 + slot * 8;
      char* dst = smem_c + buf * 65536 + isB * 32768 + khalf * 16384
                + sub * 8192 + w * 1024;   // wave-uniform; HW adds lane*16
      gload16(src, dst);
    }
  };

  const int NT = K >> 6;
  stage2(0, 0, 0); stage2(0, 0, 1); stage2(0, 0, 2); stage2(0, 0, 3);
  int cur = 0;
  const int so = (g ^ ((q >> 1) & 3)) * 16;
  for (int t = 0; t < NT; ++t) {
    const bool pre = (t + 1 < NT);
    const char* base = smem_c + cur * 65536;
    #pragma unroll
    for (int ks = 0; ks < 2; ++ks) {
      if (ks == 0 || pre) asm volatile("s_waitcnt vmcnt(4)" ::: "memory");
      else                asm volatile("s_waitcnt vmcnt(0)" ::: "memory");
      asm volatile("" ::: "memory");
      __builtin_amdgcn_s_barrier();
      asm volatile("" ::: "memory");
      const char* Ab = base + ks * 16384;
      const char* Bb = base + 32768 + ks * 16384;
      s16x8 af[8], bf0[2];
      #pragma unroll
      for (int m = 0; m < 8; ++m)
        af[m] = *(const s16x8*)(Ab + (wm * 128 + m * 16 + q) * 64 + so);
      #pragma unroll
      for (int n = 0; n < 2; ++n)
        bf0[n] = *(const s16x8*)(Bb + (wn * 64 + n * 16 + q) * 64 + so);
      if (pre) stage2(cur ^ 1, t + 1, ks * 2);
      asm volatile("s_waitcnt lgkmcnt(0)" ::: "memory");
      __builtin_amdgcn_sched_barrier(0);
      __builtin_amdgcn_s_setprio(1);
      #pragma unroll
      for (int m = 0; m < 8; ++m) {
        acc[m][0] = __builtin_amdgcn_mfma_f32_16x16x32_bf16(af[m], bf0[0], acc[m][0], 0, 0, 0);
        acc[m][1] = __builtin_amdgcn_mfma_f32_16x16x32_bf16(af[m], bf0[1], acc[m][1], 0, 0, 0);
      }
      __builtin_amdgcn_s_setprio(0);
      // sub-phase nh=1 (N-frags 2,3; reuses af)
      s16x8 bf1[2];
      #pragma unroll
      for (int n = 0; n < 2; ++n)
        bf1[n] = *(const s16x8*)(Bb + (wn * 64 + (2 + n) * 16 + q) * 64 + so);
      if (pre) stage2(cur ^ 1, t + 1, ks * 2 + 1);
      asm volatile("s_waitcnt lgkmcnt(0)" ::: "memory");
      __builtin_amdgcn_sched_barrier(0);
      __builtin_amdgcn_s_setprio(1);
      #pragma unroll
      for (int m = 0; m < 8; ++m) {
        acc[m][2] = __builtin_amdgcn_mfma_f32_16x16x32_bf16(af[m], bf1[0], acc[m][2], 0, 0, 0);
        acc[m][3] = __builtin_amdgcn_mfma_f32_16x16x32_bf16(af[m], bf1[1], acc[m][3], 0, 0, 0);
      }
      __builtin_amdgcn_s_setprio(0);
    }
    cur ^= 1;
  }

  #pragma unroll
  for (int m = 0; m < 8; ++m) {
    const int row0 = bm * 256 + wm * 128 + m * 16 + g * 4;
    #pragma unroll
    for (int n = 0; n < 4; ++n) {
      const int col = bn * 256 + wn * 64 + n * 16 + q;
      float bv = 0.0f;
      if (BIAS) bv = bias[col];
      #pragma unroll
      for (int r = 0; r < 4; ++r) {
        const size_t idx = (size_t)(row0 + r) * N + col;
        float v = acc[m][n][r] + bv;
        if (RES)  v += resid[idx];
        if (SILU) v = v / (1.0f + __expf(-v));
        if (OF32) Cf[idx] = v;
        if (OBF)  Cb[idx] = f2bf(v);
      }
    }
  }
}

// ---------------- Flash attention ----------------
// Q-tile 128 / 8 waves, 3-slot rotating KV LDS, counted vmcnt(2) + ONE raw
// barrier per KV tile. Static softmax, deferred l-reduction. Hoisted staging
// pointers (pk/pv): each stage = 2 pointer-adds + gload16.
__global__ __launch_bounds__(512, 4) void attn_k(
    const u16* __restrict__ Q, const u16* __restrict__ KV, u16* __restrict__ O)
{
  __shared__ u16 Ks[3][64 * 64];
  __shared__ u16 Vs[3][64 * 64];
  const int tid = threadIdx.x;
  const int w = tid >> 6, l = tid & 63;
  const int g = l >> 4, q = l & 15;
  // XCD-clustered mapping: xcd = blk&7 owns bh = xcd*4..xcd*4+3 (~3MB < L2)
  const int idx = blockIdx.x >> 3;
  const int bh = (blockIdx.x & 7) * 4 + (idx >> 4);
  const int qt = idx & 15;
  const int b = bh >> 4, h = bh & 15;

  // Q fragments (this wave's 16 rows x 64); pre-scaled by LOG2E/8 at cast
  const size_t qrow = (size_t)(b * 2048 + qt * 128 + w * 16 + q);
  s16x8 qf[2];
  qf[0] = *(const s16x8*)&Q[qrow * 1024 + h * 64 + g * 8];
  qf[1] = *(const s16x8*)&Q[qrow * 1024 + h * 64 + 32 + g * 8];

  f32x4 oacc[4] = {};
  f32x4 ls = {0.0f, 0.0f, 0.0f, 0.0f};

  const u16* kvb = KV + (size_t)b * 2048 * 2048;
  const unsigned vs_base =
      (unsigned)(unsigned long long)(__attribute__((address_space(3))) u16*)Vs;

  // hoisted per-thread staging source pointers (kv-row-0 addresses)
  const u16* pk; const u16* pv;
  {
    const int krow = tid >> 3, slot = tid & 7;
    pk = kvb + (size_t)krow * 2048 + h * 64 + ((slot ^ (krow & 7)) << 3);
    const int vkv = ((tid >> 3) & 15) * 4 + ((tid >> 1) & 3);
    const int vd0 = ((tid >> 7) & 3) * 16 + (tid & 1) * 8;
    pv = kvb + (size_t)vkv * 2048 + 1024 + h * 64 + vd0;
  }
  const int wdo = w * 512;   // wave-uniform LDS dest offset (elements)

  auto stage = [&](int buf, int kv0) {
    const size_t off = (size_t)kv0 << 11;      // kv0 * 2048 elements
    gload16(pk + off, &Ks[buf][0] + wdo);
    gload16(pv + off, &Vs[buf][0] + wdo);
  };

  stage(0, 0);
  stage(1, 64);
  int cur = 0;

  for (int kt = 0; kt < 32; ++kt) {
    if (kt < 31) asm volatile("s_waitcnt vmcnt(2)" ::: "memory");
    else         asm volatile("s_waitcnt vmcnt(0)" ::: "memory");
    __builtin_amdgcn_s_barrier();
    asm volatile("" ::: "memory");
    if (kt + 2 < 32) stage((cur == 0) ? 2 : cur - 1, (kt + 2) * 64);

    // S^T = K @ Q^T: sacc[nf] reg r = S^T[k = nf*16 + g*4 + r][qrow = q]
    const char* ksb = (const char*)Ks[cur];
    f32x4 sacc[4] = {};
    __builtin_amdgcn_s_setprio(1);
    #pragma unroll
    for (int s = 0; s < 2; ++s)
      #pragma unroll
      for (int nf = 0; nf < 4; ++nf) {
        const int krw = nf * 16 + q;
        const s16x8 kf = *(const s16x8*)(ksb + krw * 128 +
                              ((s * 64 + g * 16) ^ ((krw & 7) << 4)));
        sacc[nf] = __builtin_amdgcn_mfma_f32_16x16x32_bf16(kf, qf[s], sacc[nf], 0, 0, 0);
      }
    __builtin_amdgcn_s_setprio(0);

    // static softmax: P = exp2(S'); accumulate l as a vector (reduce at end)
    #pragma unroll
    for (int nf = 0; nf < 4; ++nf)
      #pragma unroll
      for (int r = 0; r < 4; ++r)
        sacc[nf][r] = __builtin_amdgcn_exp2f(sacc[nf][r]);
    ls += sacc[0]; ls += sacc[1]; ls += sacc[2]; ls += sacc[3];

    // PA fragments (lane-local repack of sacc)
    union { u32x4 u; s16x8 s8; } au[2];
    #pragma unroll
    for (int s = 0; s < 2; ++s) {
      au[s].u[0] = cvtpk(sacc[2*s  ][0], sacc[2*s  ][1]);
      au[s].u[1] = cvtpk(sacc[2*s  ][2], sacc[2*s  ][3]);
      au[s].u[2] = cvtpk(sacc[2*s+1][0], sacc[2*s+1][1]);
      au[s].u[3] = cvtpk(sacc[2*s+1][2], sacc[2*s+1][3]);
    }

    // all 16 V tr-reads + single wait, one asm block (safe batched form).
    const unsigned a0 = vs_base + (unsigned)(cur * 8192) + (unsigned)(g * 128 + 2 * q);
    u32x2 v0,v1,v2,v3,v4,v5,v6,v7,v8,v9,v10,v11,v12,v13,v14,v15;
    asm volatile(
        "ds_read_b64_tr_b16 %0,  %16\n\t"
        "ds_read_b64_tr_b16 %1,  %16 offset:512\n\t"
        "ds_read_b64_tr_b16 %2,  %16 offset:2048\n\t"
        "ds_read_b64_tr_b16 %3,  %16 offset:2560\n\t"
        "ds_read_b64_tr_b16 %4,  %16 offset:4096\n\t"
        "ds_read_b64_tr_b16 %5,  %16 offset:4608\n\t"
        "ds_read_b64_tr_b16 %6,  %16 offset:6144\n\t"
        "ds_read_b64_tr_b16 %7,  %16 offset:6656\n\t"
        "ds_read_b64_tr_b16 %8,  %16 offset:1024\n\t"
        "ds_read_b64_tr_b16 %9,  %16 offset:1536\n\t"
        "ds_read_b64_tr_b16 %10, %16 offset:3072\n\t"
        "ds_read_b64_tr_b16 %11, %16 offset:3584\n\t"
        "ds_read_b64_tr_b16 %12, %16 offset:5120\n\t"
        "ds_read_b64_tr_b16 %13, %16 offset:5632\n\t"
        "ds_read_b64_tr_b16 %14, %16 offset:7168\n\t"
        "ds_read_b64_tr_b16 %15, %16 offset:7680\n\t"
        "s_waitcnt lgkmcnt(0)"
        : "=&v"(v0), "=&v"(v1), "=&v"(v2),  "=&v"(v3),
          "=&v"(v4), "=&v"(v5), "=&v"(v6),  "=&v"(v7),
          "=&v"(v8), "=&v"(v9), "=&v"(v10), "=&v"(v11),
          "=&v"(v12),"=&v"(v13),"=&v"(v14), "=&v"(v15)
        : "v"(a0) : "memory");
    __builtin_amdgcn_sched_barrier(0);

    __builtin_amdgcn_s_setprio(1);
    {
      union { u32x4 u; s16x8 s8; } bu;
      bu.u[0]=v0[0];  bu.u[1]=v0[1];  bu.u[2]=v1[0];  bu.u[3]=v1[1];
      oacc[0] = __builtin_amdgcn_mfma_f32_16x16x32_bf16(au[0].s8, bu.s8, oacc[0], 0, 0, 0);
      bu.u[0]=v2[0];  bu.u[1]=v2[1];  bu.u[2]=v3[0];  bu.u[3]=v3[1];
      oacc[1] = __builtin_amdgcn_mfma_f32_16x16x32_bf16(au[0].s8, bu.s8, oacc[1], 0, 0, 0);
      bu.u[0]=v4[0];  bu.u[1]=v4[1];  bu.u[2]=v5[0];  bu.u[3]=v5[1];
      oacc[2] = __builtin_amdgcn_mfma_f32_16x16x32_bf16(au[0].s8, bu.s8, oacc[2], 0, 0, 0);
      bu.u[0]=v6[0];  bu.u[1]=v6[1];  bu.u[2]=v7[0];  bu.u[3]=v7[1];
      oacc[3] = __builtin_amdgcn_mfma_f32_16x16x32_bf16(au[0].s8, bu.s8, oacc[3], 0, 0, 0);
      bu.u[0]=v8[0];  bu.u[1]=v8[1];  bu.u[2]=v9[0];  bu.u[3]=v9[1];
      oacc[0] = __builtin_amdgcn_mfma_f32_16x16x32_bf16(au[1].s8, bu.s8, oacc[0], 0, 0, 0);
      bu.u[0]=v10[0]; bu.u[1]=v10[1]; bu.u[2]=v11[0]; bu.u[3]=v11[1];
      oacc[1] = __builtin_amdgcn_mfma_f32_16x16x32_bf16(au[1].s8, bu.s8, oacc[1], 0, 0, 0);
      bu.u[0]=v12[0]; bu.u[1]=v12[1]; bu.u[2]=v13[0]; bu.u[3]=v13[1];
      oacc[2] = __builtin_amdgcn_mfma_f32_16x16x32_bf16(au[1].s8, bu.s8, oacc[2], 0, 0, 0);
      bu.u[0]=v14[0]; bu.u[1]=v14[1]; bu.u[2]=v15[0]; bu.u[3]=v15[1];
      oacc[3] = __builtin_amdgcn_mfma_f32_16x16x32_bf16(au[1].s8, bu.s8, oacc[3], 0, 0, 0);
    }
    __builtin_amdgcn_s_setprio(0);

    cur = (cur == 2) ? 0 : cur + 1;
  }

  // deferred l-reduction: per-lane horizontal + cross-g (2 shfl), once
  float lsum = (ls[0] + ls[1]) + (ls[2] + ls[3]);
  lsum += __shfl_xor(lsum, 16);
  lsum += __shfl_xor(lsum, 32);
  float lr[4];
  #pragma unroll
  for (int r = 0; r < 4; ++r) lr[r] = __shfl(lsum, g * 4 + r);
  const size_t ob = (size_t)(b * 2048 + qt * 128 + w * 16) * 1024 + h * 64;
  #pragma unroll
  for (int r = 0; r < 4; ++r) {
    const float inv = 1.0f / lr[r];
    #pragma unroll
    for (int nf = 0; nf < 4; ++nf)
      O[ob + (size_t)(g * 4 + r) * 1024 + nf * 16 + q] = f2bf(oacc[nf][r] * inv);
  }
}

// ---------------- launch ----------------
extern "C" void kernel_launch(void* const* d_in, const int* in_sizes, int n_in,
                              void* d_out, int out_size, void* d_ws, size_t ws_size,
                              hipStream_t stream)
{
  const float* q_x  = (const float*)d_in[0];
  const float* kv_x = (const float*)d_in[1];
  const float* Wq   = (const float*)d_in[2];
  const float* Wkv  = (const float*)d_in[3];
  const float* Wo   = (const float*)d_in[4];
  const float* bo   = (const float*)d_in[5];
  const float* lnqg = (const float*)d_in[6];
  const float* lnqb = (const float*)d_in[7];
  const float* lnkg = (const float*)d_in[8];
  const float* lnkb = (const float*)d_in[9];
  const float* W1   = (const float*)d_in[10];
  const float* b1   = (const float*)d_in[11];
  const float* W2   = (const float*)d_in[12];
  const float* b2   = (const float*)d_in[13];
  float* out = (float*)d_out;

  char* ws = (char*)d_ws;
  const size_t MB = 1024 * 1024;
  u16*   wq_b  = (u16*)  (ws +  0 * MB);   // 2 MB
  u16*   wkv_b = (u16*)  (ws +  2 * MB);   // 4 MB
  u16*   wo_b  = (u16*)  (ws +  6 * MB);   // 2 MB
  u16*   w1_b  = (u16*)  (ws +  8 * MB);   // 8 MB
  u16*   w2_b  = (u16*)  (ws + 16 * MB);   // 8 MB
  u16*   lnq   = (u16*)  (ws + 24 * MB);   // 8 MB
  u16*   lnk   = (u16*)  (ws + 32 * MB);   // 8 MB
  u16*   qp    = (u16*)  (ws + 40 * MB);   // 8 MB
  u16*   kvp   = (u16*)  (ws + 48 * MB);   // 16 MB
  u16*   ao    = (u16*)  (ws + 64 * MB);   // 8 MB
  float* xf    = (float*)(ws + 72 * MB);   // 16 MB
  u16*   xb    = (u16*)  (ws + 88 * MB);   // 8 MB
  u16*   hb    = (u16*)  (ws + 96 * MB);   // 32 MB -> 128 MB total

  prep_k<<<dim3(20480), dim3(256), 0, stream>>>(
      Wq, Wkv, Wo, W1, W2, wq_b, wkv_b, wo_b, w1_b, w2_b,
      q_x, kv_x, lnqg, lnqb, lnkg, lnkb, lnq, lnk);

  // q = LN(q_x) @ (Wq*LOG2E/8)^T ; kv = LN(kv_x) @ Wkv^T (merged, 2-buf body)
  gemm_qkv_k<<<dim3(1536), dim3(512), 0, stream>>>(lnq, wq_b, qp, lnk, wkv_b, kvp);
  // flash attention (Q-tile 128, 8 waves)
  attn_k<<<dim3(512), dim3(512), 0, stream>>>(qp, kvp, ao);
  // x = q_x + ao @ Wo^T + bo   (2-buf body, 3 blocks/CU)
  gemm_k2<1,1,0,1,1><<<dim3(512),  dim3(512), 0, stream>>>(
      ao, wo_b, xb, xf, bo, q_x, 1024, 1024);
  // h = silu(x @ W1^T + b1)   (256^2 phase-pipelined)
  gemm256_k<1,0,1,0,1><<<dim3(256), dim3(512), 0, stream>>>(
      xb, w1_b, hb, nullptr, b1, nullptr, 4096, 1024);
  // out = x + h @ W2^T + b2    (3-slot counted-vmcnt body, K=4096)
  gemm_k3<1,1,0,1,0><<<dim3(512),  dim3(512), 0, stream>>>(
      hb, w2_b, nullptr, out, b2, xf, 1024, 4096);
}